// Round 7
// baseline (2344.399 us; speedup 1.0000x reference)
//
#include <hip/hip_runtime.h>

#define NU 50000
#define NV 50000
#define ES 800000
#define ER 1000000
#define EPS_BN 1e-5f

// ---------------- workspace layout ----------------
// floats:
static const size_t OFF_A       = 0;         // mean_soc -> t_u
static const size_t OFF_C       = 3350000;   // mean_ru -> t_v
static const size_t OFF_D       = 6550000;   // mean_v  -> x_u
static const size_t OFF_E       = 9750000;   // h_u     -> x_v
static const size_t OFF_F       = 12950000;  // h_v
static const size_t OFF_WCOMB   = 16150000;
static const size_t OFF_STATS   = 16154160;
static const size_t OFF_BNP     = 16154624;
// bytes:
static const size_t OFF_Y1_BYTES = 64640000;   // y1T: [64][ER] bf16, 128MB (CSR scratch pre-e1)
static const size_t OFF_Y2_BYTES = 192640000;  // y2T: [16][ER] bf16, 32MB
// CSR scratch inside y1 region (byte offsets rel. to OFF_Y1_BYTES), consumed before e1.
static const size_t CSR_IDX_S  = 0;
static const size_t CSR_IDX_RU = 3200000;
static const size_t CSR_IDX_V  = 7200000;
static const size_t CSR_CNT_S  = 11200000;
static const size_t CSR_CNT_RU = 11400000;
static const size_t CSR_CNT_V  = 11600000;
static const size_t CSR_CUR_S  = 11800000;
static const size_t CSR_CUR_RU = 12000000;
static const size_t CSR_CUR_V  = 12200000;
static const size_t CSR_OFF_S  = 12400000;
static const size_t CSR_OFF_RU = 12600016;
static const size_t CSR_OFF_V  = 12800032;

#define REP16(M) M(0) M(1) M(2) M(3) M(4) M(5) M(6) M(7) M(8) M(9) M(10) M(11) M(12) M(13) M(14) M(15)
#define REP4(M) M(0) M(1) M(2) M(3)

// ---------------- helpers ----------------
__device__ __forceinline__ unsigned short f2bf(float f) {
  unsigned u = __float_as_uint(f);
  unsigned r = u + 0x7FFF + ((u >> 16) & 1);   // RNE (finite values)
  return (unsigned short)(r >> 16);
}
__device__ __forceinline__ float bf2f(unsigned short h) {
  return __uint_as_float(((unsigned)h) << 16);
}

__device__ __forceinline__ void fma_row(float xk, const float* __restrict__ wrow, float4* acc) {
  const float4* w = (const float4*)wrow;
#pragma unroll
  for (int j = 0; j < 16; ++j) {
    float4 wv = w[j];
    acc[j].x = fmaf(xk, wv.x, acc[j].x);
    acc[j].y = fmaf(xk, wv.y, acc[j].y);
    acc[j].z = fmaf(xk, wv.z, acc[j].z);
    acc[j].w = fmaf(xk, wv.w, acc[j].w);
  }
}

// ---------------- kernels ----------------
__global__ __launch_bounds__(256) void wcomb_kernel(const float* __restrict__ W_self,
                                                    const float* __restrict__ b_self,
                                                    float* __restrict__ wcomb) {
  int i = blockIdx.x * 256 + threadIdx.x;
  if (i < 4096) wcomb[i] = W_self[i] + W_self[8192 + i];
  if (i < 64) wcomb[4096 + i] = b_self[i] + b_self[128 + i];
}

__global__ __launch_bounds__(256) void hist_kernel(const int* __restrict__ sd,
                                                   const int* __restrict__ rs,
                                                   const int* __restrict__ rd,
                                                   int* __restrict__ cnt_s,
                                                   int* __restrict__ cnt_ru,
                                                   int* __restrict__ cnt_v) {
  int stride = gridDim.x * 256;
  for (int e = blockIdx.x * 256 + threadIdx.x; e < ER; e += stride) {
    if (e < ES) atomicAdd(&cnt_s[sd[e]], 1);
    atomicAdd(&cnt_ru[rs[e]], 1);
    atomicAdd(&cnt_v[rd[e]], 1);
  }
}

__global__ __launch_bounds__(1024) void scan3_kernel(const int* __restrict__ c0, int n0, int* o0, int* u0,
                                                     const int* __restrict__ c1, int n1, int* o1, int* u1,
                                                     const int* __restrict__ c2, int n2, int* o2, int* u2) {
  const int* c; int n; int* o; int* u;
  if (blockIdx.x == 0) { c = c0; n = n0; o = o0; u = u0; }
  else if (blockIdx.x == 1) { c = c1; n = n1; o = o1; u = u1; }
  else { c = c2; n = n2; o = o2; u = u2; }
  __shared__ int buf[1024];
  __shared__ int carry_s;
  if (threadIdx.x == 0) carry_s = 0;
  __syncthreads();
  for (int base = 0; base < n; base += 1024) {
    int i = base + threadIdx.x;
    int v = (i < n) ? c[i] : 0;
    buf[threadIdx.x] = v;
    __syncthreads();
#pragma unroll
    for (int ofs = 1; ofs < 1024; ofs <<= 1) {
      int t = 0;
      if ((int)threadIdx.x >= ofs) t = buf[threadIdx.x - ofs];
      __syncthreads();
      buf[threadIdx.x] += t;
      __syncthreads();
    }
    int carry = carry_s;
    int excl = carry + buf[threadIdx.x] - v;
    if (i < n) { o[i] = excl; u[i] = excl; }
    __syncthreads();
    if (threadIdx.x == 0) carry_s += buf[1023];
    __syncthreads();
  }
  if (threadIdx.x == 0) o[n] = carry_s;
}

__global__ __launch_bounds__(256) void scatter_kernel(const int* __restrict__ ss,
                                                      const int* __restrict__ sd,
                                                      const int* __restrict__ rs,
                                                      const int* __restrict__ rd,
                                                      int* __restrict__ cur_s,
                                                      int* __restrict__ cur_ru,
                                                      int* __restrict__ cur_v,
                                                      int* __restrict__ idx_s,
                                                      int* __restrict__ idx_ru,
                                                      int* __restrict__ idx_v) {
  int stride = gridDim.x * 256;
  for (int e = blockIdx.x * 256 + threadIdx.x; e < ER; e += stride) {
    if (e < ES) {
      int p = atomicAdd(&cur_s[sd[e]], 1);
      idx_s[p] = ss[e];
    }
    int s = rs[e], d = rd[e];
    int p = atomicAdd(&cur_ru[s], 1);
    idx_ru[p] = d;
    int q = atomicAdd(&cur_v[d], 1);
    idx_v[q] = s;
  }
}

__global__ __launch_bounds__(256) void gmean_kernel(const float* __restrict__ tab,
                                                    const int* __restrict__ off,
                                                    const int* __restrict__ idx, int N,
                                                    float* __restrict__ mean) {
  int wid = (blockIdx.x * 256 + threadIdx.x) >> 6;
  int lane = threadIdx.x & 63;
  if (wid >= N) return;
  int b = off[wid], e = off[wid + 1];
  float acc0 = 0.0f, acc1 = 0.0f, acc2 = 0.0f, acc3 = 0.0f;
  int i = b;
  for (; i + 3 < e; i += 4) {
    int n0 = idx[i], n1 = idx[i + 1], n2 = idx[i + 2], n3 = idx[i + 3];
    acc0 += tab[(size_t)n0 * 64 + lane];
    acc1 += tab[(size_t)n1 * 64 + lane];
    acc2 += tab[(size_t)n2 * 64 + lane];
    acc3 += tab[(size_t)n3 * 64 + lane];
  }
  for (; i < e; ++i) acc0 += tab[(size_t)idx[i] * 64 + lane];
  float acc = (acc0 + acc1) + (acc2 + acc3);
  float inv = (e > b) ? 1.0f / (float)(e - b) : 0.0f;
  mean[(size_t)wid * 64 + lane] = acc * inv;
}

__global__ __launch_bounds__(256) void hu_kernel(const float* __restrict__ u2e,
                                                 const float* __restrict__ wcomb,
                                                 const float* __restrict__ W_neigh,
                                                 const float* __restrict__ mean_soc,
                                                 const float* __restrict__ mean_ru,
                                                 float* __restrict__ h_u) {
  __shared__ float Wc[4096], W0[4096], W2[4096], bc[64];
  for (int i = threadIdx.x; i < 4096; i += 256) {
    Wc[i] = wcomb[i];
    W0[i] = W_neigh[i];
    W2[i] = W_neigh[8192 + i];
  }
  if (threadIdx.x < 64) bc[threadIdx.x] = wcomb[4096 + threadIdx.x];
  __syncthreads();
  int row = blockIdx.x * 256 + threadIdx.x;
  if (row >= NU) return;
  float4 acc[16];
#pragma unroll
  for (int j = 0; j < 16; ++j) acc[j] = ((const float4*)bc)[j];
  const float4* xr = (const float4*)&u2e[(size_t)row * 64];
  const float4* n0 = (const float4*)&mean_soc[(size_t)row * 64];
  const float4* n2 = (const float4*)&mean_ru[(size_t)row * 64];
#pragma unroll 1
  for (int k4 = 0; k4 < 16; ++k4) {
    float4 a = xr[k4], b0 = n0[k4], b2 = n2[k4];
#pragma unroll
    for (int kk = 0; kk < 4; ++kk) {
      int k = k4 * 4 + kk;
      fma_row((&a.x)[kk], &Wc[k * 64], acc);
      fma_row((&b0.x)[kk], &W0[k * 64], acc);
      fma_row((&b2.x)[kk], &W2[k * 64], acc);
    }
  }
  float4* o = (float4*)&h_u[(size_t)row * 64];
#pragma unroll
  for (int j = 0; j < 16; ++j) o[j] = acc[j];
}

__global__ __launch_bounds__(256) void hv_kernel(const float* __restrict__ v2e,
                                                 const float* __restrict__ W_self,
                                                 const float* __restrict__ b_self,
                                                 const float* __restrict__ W_neigh,
                                                 const float* __restrict__ mean_v,
                                                 float* __restrict__ h_v) {
  __shared__ float Ws[4096], Wn[4096], bl[64];
  for (int i = threadIdx.x; i < 4096; i += 256) {
    Ws[i] = W_self[4096 + i];
    Wn[i] = W_neigh[4096 + i];
  }
  if (threadIdx.x < 64) bl[threadIdx.x] = b_self[64 + threadIdx.x];
  __syncthreads();
  int row = blockIdx.x * 256 + threadIdx.x;
  if (row >= NV) return;
  float4 acc[16];
#pragma unroll
  for (int j = 0; j < 16; ++j) acc[j] = ((const float4*)bl)[j];
  const float4* xr = (const float4*)&v2e[(size_t)row * 64];
  const float4* nv = (const float4*)&mean_v[(size_t)row * 64];
#pragma unroll 1
  for (int k4 = 0; k4 < 16; ++k4) {
    float4 a = xr[k4], b0 = nv[k4];
#pragma unroll
    for (int kk = 0; kk < 4; ++kk) {
      int k = k4 * 4 + kk;
      fma_row((&a.x)[kk], &Ws[k * 64], acc);
      fma_row((&b0.x)[kk], &Wn[k * 64], acc);
    }
  }
  float4* o = (float4*)&h_v[(size_t)row * 64];
#pragma unroll
  for (int j = 0; j < 16; ++j) o[j] = acc[j];
}

// ---- lin_stats: thread-per-row, acc in NAMED float4 registers.
#define CSTAT(VAL, IDX) { \
  float s_ = valid ? (VAL) : 0.0f; float q_ = s_ * s_; \
  s_ += __shfl_down(s_, 32, 64); q_ += __shfl_down(q_, 32, 64); \
  s_ += __shfl_down(s_, 16, 64); q_ += __shfl_down(q_, 16, 64); \
  s_ += __shfl_down(s_, 8, 64);  q_ += __shfl_down(q_, 8, 64); \
  s_ += __shfl_down(s_, 4, 64);  q_ += __shfl_down(q_, 4, 64); \
  s_ += __shfl_down(s_, 2, 64);  q_ += __shfl_down(q_, 2, 64); \
  s_ += __shfl_down(s_, 1, 64);  q_ += __shfl_down(q_, 1, 64); \
  if ((threadIdx.x & 63) == 0) { atomicAdd(&s1[IDX], s_); atomicAdd(&s2[IDX], q_); } }

__global__ __launch_bounds__(256) void lin_stats_kernel(const float* __restrict__ in,
                                                        const float* __restrict__ W,
                                                        const float* __restrict__ b, int N,
                                                        float* __restrict__ out,
                                                        float* __restrict__ ssum,
                                                        float* __restrict__ ssq) {
  __shared__ float Wl[4096], bl[64], s1[64], s2[64];
  for (int i = threadIdx.x; i < 4096; i += 256) Wl[i] = W[i];
  if (threadIdx.x < 64) {
    bl[threadIdx.x] = b[threadIdx.x];
    s1[threadIdx.x] = 0.0f;
    s2[threadIdx.x] = 0.0f;
  }
  __syncthreads();
  int row = blockIdx.x * 256 + threadIdx.x;
  bool valid = row < N;
  const float4* bl4 = (const float4*)bl;
#define LS_DECL(I) float4 A##I;
  REP16(LS_DECL)
#define LS_INIT(I) A##I = bl4[I];
  REP16(LS_INIT)
  if (valid) {
    const float4* xr = (const float4*)&in[(size_t)row * 64];
#define LS_FMA(I) { float4 w_ = W4_[I]; \
    A##I.x = fmaf(z_, w_.x, A##I.x); A##I.y = fmaf(z_, w_.y, A##I.y); \
    A##I.z = fmaf(z_, w_.z, A##I.z); A##I.w = fmaf(z_, w_.w, A##I.w); }
#define LS_DOFMA(ZV, K) { float z_ = (ZV); const float4* W4_ = (const float4*)&Wl[(K) * 64]; REP16(LS_FMA) }
#pragma unroll
    for (int k4 = 0; k4 < 16; ++k4) {
      float4 xa = xr[k4];
      LS_DOFMA(xa.x, k4 * 4 + 0)
      LS_DOFMA(xa.y, k4 * 4 + 1)
      LS_DOFMA(xa.z, k4 * 4 + 2)
      LS_DOFMA(xa.w, k4 * 4 + 3)
    }
    float4* o4 = (float4*)&out[(size_t)row * 64];
#define LS_ST(I) o4[I] = A##I;
    REP16(LS_ST)
  }
#define LS_CST(I) CSTAT(A##I.x, 4 * (I) + 0) CSTAT(A##I.y, 4 * (I) + 1) \
                  CSTAT(A##I.z, 4 * (I) + 2) CSTAT(A##I.w, 4 * (I) + 3)
  REP16(LS_CST)
  __syncthreads();
  if (threadIdx.x < 64) {
    atomicAdd(&ssum[threadIdx.x], s1[threadIdx.x]);
    atomicAdd(&ssq[threadIdx.x], s2[threadIdx.x]);
  }
}

__global__ __launch_bounds__(256) void bn_final_kernel(const float* __restrict__ ssum,
                                                       const float* __restrict__ ssq,
                                                       const float* __restrict__ gamma,
                                                       const float* __restrict__ beta,
                                                       float n, int C, float* __restrict__ bnp) {
  int j = threadIdx.x;
  if (j >= C) return;
  float m = ssum[j] / n;
  float var = ssq[j] / n - m * m;
  float s = gamma[j] * rsqrtf(var + EPS_BN);
  bnp[j] = s;
  bnp[C + j] = beta[j] - m * s;
}

__global__ __launch_bounds__(256) void bnrelu_lin_kernel(const float* __restrict__ tin,
                                                         const float* __restrict__ bnp,
                                                         const float* __restrict__ W,
                                                         const float* __restrict__ b, int N,
                                                         float* __restrict__ xout) {
  __shared__ float Wl[4096], bl[64], sc[64], sh[64];
  for (int i = threadIdx.x; i < 4096; i += 256) Wl[i] = W[i];
  if (threadIdx.x < 64) {
    bl[threadIdx.x] = b[threadIdx.x];
    sc[threadIdx.x] = bnp[threadIdx.x];
    sh[threadIdx.x] = bnp[64 + threadIdx.x];
  }
  __syncthreads();
  int row = blockIdx.x * 256 + threadIdx.x;
  if (row >= N) return;
  float4 acc[16];
#pragma unroll
  for (int j = 0; j < 16; ++j) acc[j] = ((const float4*)bl)[j];
  const float4* xr = (const float4*)&tin[(size_t)row * 64];
#pragma unroll 1
  for (int k4 = 0; k4 < 16; ++k4) {
    float4 a = xr[k4];
#pragma unroll
    for (int kk = 0; kk < 4; ++kk) {
      int k = k4 * 4 + kk;
      float z = fmaxf(fmaf((&a.x)[kk], sc[k], sh[k]), 0.0f);
      fma_row(z, &Wl[k * 64], acc);
    }
  }
  float4* o = (float4*)&xout[(size_t)row * 64];
#pragma unroll
  for (int j = 0; j < 16; ++j) o[j] = acc[j];
}

// ---- e1 v2: wave-per-edge via LDS broadcast (no readlane).
// Per 64-edge tile: phase1 each wave gathers+muls its own 16 P rows into LDS;
// phase2 (wave-local, no barrier) ds_read_b128-broadcast its rows, 64 FMAs/edge,
// overwrite row with output; barrier; phase3 transposed coalesced NT write; barrier.
__global__ __launch_bounds__(256) void e1_kernel(const float* __restrict__ xu,
                                                 const float* __restrict__ xv,
                                                 const int* __restrict__ rs,
                                                 const int* __restrict__ rd,
                                                 const float* __restrict__ W,
                                                 const float* __restrict__ b,
                                                 unsigned short* __restrict__ y1T,
                                                 float* __restrict__ ssum,
                                                 float* __restrict__ ssq) {
  __shared__ float P[64][65];
  __shared__ float s1[64], s2[64];
  int lane = threadIdx.x & 63;
  int wave = threadIdx.x >> 6;   // 0..3
  if (threadIdx.x < 64) { s1[threadIdx.x] = 0.0f; s2[threadIdx.x] = 0.0f; }
#define E1_DECLW(I) float4 WA##I;
  REP16(E1_DECLW)
#define E1_LDW(I) WA##I.x = W[(4 * (I) + 0) * 64 + lane]; \
                  WA##I.y = W[(4 * (I) + 1) * 64 + lane]; \
                  WA##I.z = W[(4 * (I) + 2) * 64 + lane]; \
                  WA##I.w = W[(4 * (I) + 3) * 64 + lane];
  REP16(E1_LDW)
  float bl = b[lane];
  float ssl = 0.0f, sql = 0.0f;
  __syncthreads();
  const int ntiles = ER / 64;    // 15625 exactly
  for (int t = blockIdx.x; t < ntiles; t += gridDim.x) {
    int e0 = t * 64;
    int ebase = e0 + wave * 16;
    // phase 1: gather + elementwise mul into this wave's 16 P rows
#pragma unroll
    for (int i = 0; i < 16; ++i) {
      int e = ebase + i;
      P[wave * 16 + i][lane] = xu[(size_t)rs[e] * 64 + lane] * xv[(size_t)rd[e] * 64 + lane];
    }
    // phase 2: wave-local consume (broadcast b128 reads), overwrite row with output
#pragma unroll 2
    for (int i = 0; i < 16; ++i) {
      int el = wave * 16 + i;
      const float4* Pr = (const float4*)&P[el][0];
      float a0_ = bl, a1_ = 0.0f;
#define E1_K(I) { float4 pv = Pr[I]; \
      a0_ = fmaf(pv.x, WA##I.x, a0_); a1_ = fmaf(pv.y, WA##I.y, a1_); \
      a0_ = fmaf(pv.z, WA##I.z, a0_); a1_ = fmaf(pv.w, WA##I.w, a1_); }
      REP16(E1_K)
      float acc = a0_ + a1_;
      ssl += acc;
      sql = fmaf(acc, acc, sql);
      P[el][lane] = acc;   // safe: whole row consumed above (in-wave ordering)
    }
    __syncthreads();
    // phase 3: transposed coalesced write (128B per j), non-temporal
#pragma unroll 1
    for (int i = 0; i < 16; ++i) {
      int j = wave * 16 + i;
      __builtin_nontemporal_store(f2bf(P[lane][j]), &y1T[(size_t)j * ER + e0 + lane]);
    }
    __syncthreads();
  }
  atomicAdd(&s1[lane], ssl);
  atomicAdd(&s2[lane], sql);
  __syncthreads();
  if (threadIdx.x < 64) {
    atomicAdd(&ssum[threadIdx.x], s1[threadIdx.x]);
    atomicAdd(&ssq[threadIdx.x], s2[threadIdx.x]);
  }
}

// ---- e2: thread-per-edge on column-major y1T, NAMED register accumulators.
#define ESTAT(SV, QV, IDX) { \
  float s_ = (SV); float q_ = (QV); \
  s_ += __shfl_down(s_, 32, 64); q_ += __shfl_down(q_, 32, 64); \
  s_ += __shfl_down(s_, 16, 64); q_ += __shfl_down(q_, 16, 64); \
  s_ += __shfl_down(s_, 8, 64);  q_ += __shfl_down(q_, 8, 64); \
  s_ += __shfl_down(s_, 4, 64);  q_ += __shfl_down(q_, 4, 64); \
  s_ += __shfl_down(s_, 2, 64);  q_ += __shfl_down(q_, 2, 64); \
  s_ += __shfl_down(s_, 1, 64);  q_ += __shfl_down(q_, 1, 64); \
  if ((threadIdx.x & 63) == 0) { atomicAdd(&s1[IDX], s_); atomicAdd(&s2[IDX], q_); } }

__global__ __launch_bounds__(256) void e2_kernel(const unsigned short* __restrict__ y1T,
                                                 const float* __restrict__ bnp3,
                                                 const float* __restrict__ W,   // [64,16]
                                                 const float* __restrict__ b,   // [16]
                                                 unsigned short* __restrict__ y2T,
                                                 float* __restrict__ ssum,
                                                 float* __restrict__ ssq) {
  __shared__ float Wl[1024], bl[16], sc[64], sh[64], s1[16], s2[16];
  for (int i = threadIdx.x; i < 1024; i += 256) Wl[i] = W[i];
  if (threadIdx.x < 16) {
    bl[threadIdx.x] = b[threadIdx.x];
    s1[threadIdx.x] = 0.0f;
    s2[threadIdx.x] = 0.0f;
  }
  if (threadIdx.x < 64) { sc[threadIdx.x] = bnp3[threadIdx.x]; sh[threadIdx.x] = bnp3[64 + threadIdx.x]; }
  __syncthreads();
  const float4* bl4 = (const float4*)bl;
  const float4* Wl4 = (const float4*)Wl;
#define E2_DECL(I) float4 B##I; \
  float4 SA##I = make_float4(0.f, 0.f, 0.f, 0.f); \
  float4 SQ##I = make_float4(0.f, 0.f, 0.f, 0.f);
  REP4(E2_DECL)
  int stride = gridDim.x * 256;
  for (int e = blockIdx.x * 256 + threadIdx.x; e < ER; e += stride) {
#define E2_INIT(I) B##I = bl4[I];
    REP4(E2_INIT)
#pragma unroll 4
    for (int k = 0; k < 64; ++k) {
      unsigned short yv = __builtin_nontemporal_load(&y1T[(size_t)k * ER + e]);
      float z = fmaxf(fmaf(bf2f(yv), sc[k], sh[k]), 0.0f);
#define E2_FMA(I) { float4 w_ = Wl4[(k << 2) + (I)]; \
      B##I.x = fmaf(z, w_.x, B##I.x); B##I.y = fmaf(z, w_.y, B##I.y); \
      B##I.z = fmaf(z, w_.z, B##I.z); B##I.w = fmaf(z, w_.w, B##I.w); }
      REP4(E2_FMA)
    }
#define E2_OUT(I) \
    __builtin_nontemporal_store(f2bf(B##I.x), &y2T[(size_t)(4 * (I) + 0) * ER + e]); SA##I.x += B##I.x; SQ##I.x = fmaf(B##I.x, B##I.x, SQ##I.x); \
    __builtin_nontemporal_store(f2bf(B##I.y), &y2T[(size_t)(4 * (I) + 1) * ER + e]); SA##I.y += B##I.y; SQ##I.y = fmaf(B##I.y, B##I.y, SQ##I.y); \
    __builtin_nontemporal_store(f2bf(B##I.z), &y2T[(size_t)(4 * (I) + 2) * ER + e]); SA##I.z += B##I.z; SQ##I.z = fmaf(B##I.z, B##I.z, SQ##I.z); \
    __builtin_nontemporal_store(f2bf(B##I.w), &y2T[(size_t)(4 * (I) + 3) * ER + e]); SA##I.w += B##I.w; SQ##I.w = fmaf(B##I.w, B##I.w, SQ##I.w);
    REP4(E2_OUT)
  }
#define E2_RED(I) ESTAT(SA##I.x, SQ##I.x, 4 * (I) + 0) ESTAT(SA##I.y, SQ##I.y, 4 * (I) + 1) \
                  ESTAT(SA##I.z, SQ##I.z, 4 * (I) + 2) ESTAT(SA##I.w, SQ##I.w, 4 * (I) + 3)
  REP4(E2_RED)
  __syncthreads();
  if (threadIdx.x < 16) {
    atomicAdd(&ssum[threadIdx.x], s1[threadIdx.x]);
    atomicAdd(&ssq[threadIdx.x], s2[threadIdx.x]);
  }
}

__global__ __launch_bounds__(256) void e3_kernel(const unsigned short* __restrict__ y2T,
                                                 const float* __restrict__ bnp4,
                                                 const float* __restrict__ w3,
                                                 const float* __restrict__ b3,
                                                 float* __restrict__ out) {
  __shared__ float sc[16], sh[16], wl[16];
  if (threadIdx.x < 16) {
    sc[threadIdx.x] = bnp4[threadIdx.x];
    sh[threadIdx.x] = bnp4[16 + threadIdx.x];
    wl[threadIdx.x] = w3[threadIdx.x];
  }
  __syncthreads();
  int e = blockIdx.x * 256 + threadIdx.x;
  if (e >= ER) return;
  float acc = b3[0];
#pragma unroll
  for (int j = 0; j < 16; ++j) {
    unsigned short yv = __builtin_nontemporal_load(&y2T[(size_t)j * ER + e]);
    float z = fmaxf(fmaf(bf2f(yv), sc[j], sh[j]), 0.0f);
    acc = fmaf(z, wl[j], acc);
  }
  out[e] = acc;
}

// ---------------- host ----------------
extern "C" void kernel_launch(void* const* d_in, const int* in_sizes, int n_in,
                              void* d_out, int out_size, void* d_ws, size_t ws_size,
                              hipStream_t stream) {
  const float* u2e = (const float*)d_in[0];
  const float* v2e = (const float*)d_in[1];
  const float* W_self = (const float*)d_in[2];
  const float* b_self = (const float*)d_in[3];
  const float* W_neigh = (const float*)d_in[4];
  const float* Wur1 = (const float*)d_in[5];
  const float* bur1 = (const float*)d_in[6];
  const float* Wur2 = (const float*)d_in[7];
  const float* bur2 = (const float*)d_in[8];
  const float* Wvr1 = (const float*)d_in[9];
  const float* bvr1 = (const float*)d_in[10];
  const float* Wvr2 = (const float*)d_in[11];
  const float* bvr2 = (const float*)d_in[12];
  const float* Wuv1 = (const float*)d_in[13];
  const float* buv1 = (const float*)d_in[14];
  const float* Wuv2 = (const float*)d_in[15];
  const float* buv2 = (const float*)d_in[16];
  const float* Wuv3 = (const float*)d_in[17];
  const float* buv3 = (const float*)d_in[18];
  const float* bn_gamma = (const float*)d_in[19];
  const float* bn_beta = (const float*)d_in[20];
  const float* bn4_gamma = (const float*)d_in[21];
  const float* bn4_beta = (const float*)d_in[22];
  const int* social_src = (const int*)d_in[23];
  const int* social_dst = (const int*)d_in[24];
  const int* rates_src = (const int*)d_in[25];
  const int* rates_dst = (const int*)d_in[26];
  float* out = (float*)d_out;
  float* ws = (float*)d_ws;

  float* A = ws + OFF_A;
  float* Cb = ws + OFF_C;
  float* Db = ws + OFF_D;
  float* Eb = ws + OFF_E;
  float* Fb = ws + OFF_F;
  float* wcomb = ws + OFF_WCOMB;
  float* stats = ws + OFF_STATS;
  float* bnp = ws + OFF_BNP;
  char* y1base = (char*)d_ws + OFF_Y1_BYTES;
  int* idx_s  = (int*)(y1base + CSR_IDX_S);
  int* idx_ru = (int*)(y1base + CSR_IDX_RU);
  int* idx_v  = (int*)(y1base + CSR_IDX_V);
  int* cnt_s  = (int*)(y1base + CSR_CNT_S);
  int* cnt_ru = (int*)(y1base + CSR_CNT_RU);
  int* cnt_v  = (int*)(y1base + CSR_CNT_V);
  int* cur_s  = (int*)(y1base + CSR_CUR_S);
  int* cur_ru = (int*)(y1base + CSR_CUR_RU);
  int* cur_v  = (int*)(y1base + CSR_CUR_V);
  int* off_s  = (int*)(y1base + CSR_OFF_S);
  int* off_ru = (int*)(y1base + CSR_OFF_RU);
  int* off_v  = (int*)(y1base + CSR_OFF_V);
  unsigned short* y1T = (unsigned short*)y1base;
  unsigned short* y2T = (unsigned short*)((char*)d_ws + OFF_Y2_BYTES);

  hipMemsetAsync(cnt_s, 0, 3 * (size_t)NU * sizeof(int), stream);
  hipMemsetAsync(stats, 0, 464 * sizeof(float), stream);

  wcomb_kernel<<<16, 256, 0, stream>>>(W_self, b_self, wcomb);

  hist_kernel<<<2048, 256, 0, stream>>>(social_dst, rates_src, rates_dst, cnt_s, cnt_ru, cnt_v);
  scan3_kernel<<<3, 1024, 0, stream>>>(cnt_s, NU, off_s, cur_s,
                                       cnt_ru, NU, off_ru, cur_ru,
                                       cnt_v, NV, off_v, cur_v);
  scatter_kernel<<<2048, 256, 0, stream>>>(social_src, social_dst, rates_src, rates_dst,
                                           cur_s, cur_ru, cur_v, idx_s, idx_ru, idx_v);
  gmean_kernel<<<(NU * 64 + 255) / 256, 256, 0, stream>>>(u2e, off_s, idx_s, NU, A);
  gmean_kernel<<<(NU * 64 + 255) / 256, 256, 0, stream>>>(v2e, off_ru, idx_ru, NU, Cb);
  gmean_kernel<<<(NV * 64 + 255) / 256, 256, 0, stream>>>(u2e, off_v, idx_v, NV, Db);

  hu_kernel<<<(NU + 255) / 256, 256, 0, stream>>>(u2e, wcomb, W_neigh, A, Cb, Eb);
  hv_kernel<<<(NV + 255) / 256, 256, 0, stream>>>(v2e, W_self, b_self, W_neigh, Db, Fb);

  lin_stats_kernel<<<(NU + 255) / 256, 256, 0, stream>>>(Eb, Wur1, bur1, NU, A, stats + 0, stats + 64);
  lin_stats_kernel<<<(NV + 255) / 256, 256, 0, stream>>>(Fb, Wvr1, bvr1, NV, Cb, stats + 128, stats + 192);

  bn_final_kernel<<<1, 64, 0, stream>>>(stats + 0, stats + 64, bn_gamma, bn_beta, (float)NU, 64, bnp);
  bn_final_kernel<<<1, 64, 0, stream>>>(stats + 128, stats + 192, bn_gamma + 64, bn_beta + 64, (float)NV, 64, bnp + 128);

  bnrelu_lin_kernel<<<(NU + 255) / 256, 256, 0, stream>>>(A, bnp, Wur2, bur2, NU, Db);
  bnrelu_lin_kernel<<<(NV + 255) / 256, 256, 0, stream>>>(Cb, bnp + 128, Wvr2, bvr2, NV, Eb);

  e1_kernel<<<2048, 256, 0, stream>>>(Db, Eb, rates_src, rates_dst, Wuv1, buv1, y1T,
                                      stats + 256, stats + 320);
  bn_final_kernel<<<1, 64, 0, stream>>>(stats + 256, stats + 320, bn_gamma + 128, bn_beta + 128,
                                        (float)ER, 64, bnp + 256);
  e2_kernel<<<2048, 256, 0, stream>>>(y1T, bnp + 256, Wuv2, buv2, y2T,
                                      stats + 384, stats + 400);
  bn_final_kernel<<<1, 16, 0, stream>>>(stats + 384, stats + 400, bn4_gamma, bn4_beta,
                                        (float)ER, 16, bnp + 384);
  e3_kernel<<<(ER + 255) / 256, 256, 0, stream>>>(y2T, bnp + 384, Wuv3, buv3, out);
}

// Round 8
// 1144.984 us; speedup vs baseline: 2.0475x; 2.0475x over previous
//
#include <hip/hip_runtime.h>

#define NU 50000
#define NV 50000
#define ES 800000
#define ER 1000000
#define EPS_BN 1e-5f

// ---------------- workspace layout ----------------
// floats:
static const size_t OFF_A       = 0;         // mean_soc -> t_u
static const size_t OFF_C       = 3350000;   // mean_ru -> t_v
static const size_t OFF_D       = 6550000;   // mean_v  -> x_u
static const size_t OFF_E       = 9750000;   // h_u     -> x_v
static const size_t OFF_F       = 12950000;  // h_v
static const size_t OFF_WCOMB   = 16150000;
static const size_t OFF_STATS   = 16154160;
static const size_t OFF_BNP     = 16154624;
// bytes:
static const size_t OFF_Y1_BYTES = 64640000;   // y1T: [64][ER] bf16, 128MB (CSR scratch pre-e1)
static const size_t OFF_Y2_BYTES = 192640000;  // y2T: [16][ER] bf16, 32MB
// CSR scratch inside y1 region (byte offsets rel. to OFF_Y1_BYTES), consumed before e1.
static const size_t CSR_IDX_S  = 0;
static const size_t CSR_IDX_RU = 3200000;
static const size_t CSR_IDX_V  = 7200000;
static const size_t CSR_CNT_S  = 11200000;
static const size_t CSR_CNT_RU = 11400000;
static const size_t CSR_CNT_V  = 11600000;
static const size_t CSR_CUR_S  = 11800000;
static const size_t CSR_CUR_RU = 12000000;
static const size_t CSR_CUR_V  = 12200000;
static const size_t CSR_OFF_S  = 12400000;
static const size_t CSR_OFF_RU = 12600016;
static const size_t CSR_OFF_V  = 12800032;

#define REP16(M) M(0) M(1) M(2) M(3) M(4) M(5) M(6) M(7) M(8) M(9) M(10) M(11) M(12) M(13) M(14) M(15)
#define REP4(M) M(0) M(1) M(2) M(3)

typedef __attribute__((ext_vector_type(8))) short bf16x8;
typedef __attribute__((ext_vector_type(4))) float f32x4;

// ---------------- helpers ----------------
__device__ __forceinline__ unsigned short f2bf(float f) {
  unsigned u = __float_as_uint(f);
  unsigned r = u + 0x7FFF + ((u >> 16) & 1);   // RNE (finite values)
  return (unsigned short)(r >> 16);
}
__device__ __forceinline__ float bf2f(unsigned short h) {
  return __uint_as_float(((unsigned)h) << 16);
}

__device__ __forceinline__ void fma_row(float xk, const float* __restrict__ wrow, float4* acc) {
  const float4* w = (const float4*)wrow;
#pragma unroll
  for (int j = 0; j < 16; ++j) {
    float4 wv = w[j];
    acc[j].x = fmaf(xk, wv.x, acc[j].x);
    acc[j].y = fmaf(xk, wv.y, acc[j].y);
    acc[j].z = fmaf(xk, wv.z, acc[j].z);
    acc[j].w = fmaf(xk, wv.w, acc[j].w);
  }
}

// ---------------- kernels ----------------
__global__ __launch_bounds__(256) void wcomb_kernel(const float* __restrict__ W_self,
                                                    const float* __restrict__ b_self,
                                                    float* __restrict__ wcomb) {
  int i = blockIdx.x * 256 + threadIdx.x;
  if (i < 4096) wcomb[i] = W_self[i] + W_self[8192 + i];
  if (i < 64) wcomb[4096 + i] = b_self[i] + b_self[128 + i];
}

__global__ __launch_bounds__(256) void hist_kernel(const int* __restrict__ sd,
                                                   const int* __restrict__ rs,
                                                   const int* __restrict__ rd,
                                                   int* __restrict__ cnt_s,
                                                   int* __restrict__ cnt_ru,
                                                   int* __restrict__ cnt_v) {
  int stride = gridDim.x * 256;
  for (int e = blockIdx.x * 256 + threadIdx.x; e < ER; e += stride) {
    if (e < ES) atomicAdd(&cnt_s[sd[e]], 1);
    atomicAdd(&cnt_ru[rs[e]], 1);
    atomicAdd(&cnt_v[rd[e]], 1);
  }
}

__global__ __launch_bounds__(1024) void scan3_kernel(const int* __restrict__ c0, int n0, int* o0, int* u0,
                                                     const int* __restrict__ c1, int n1, int* o1, int* u1,
                                                     const int* __restrict__ c2, int n2, int* o2, int* u2) {
  const int* c; int n; int* o; int* u;
  if (blockIdx.x == 0) { c = c0; n = n0; o = o0; u = u0; }
  else if (blockIdx.x == 1) { c = c1; n = n1; o = o1; u = u1; }
  else { c = c2; n = n2; o = o2; u = u2; }
  __shared__ int buf[1024];
  __shared__ int carry_s;
  if (threadIdx.x == 0) carry_s = 0;
  __syncthreads();
  for (int base = 0; base < n; base += 1024) {
    int i = base + threadIdx.x;
    int v = (i < n) ? c[i] : 0;
    buf[threadIdx.x] = v;
    __syncthreads();
#pragma unroll
    for (int ofs = 1; ofs < 1024; ofs <<= 1) {
      int t = 0;
      if ((int)threadIdx.x >= ofs) t = buf[threadIdx.x - ofs];
      __syncthreads();
      buf[threadIdx.x] += t;
      __syncthreads();
    }
    int carry = carry_s;
    int excl = carry + buf[threadIdx.x] - v;
    if (i < n) { o[i] = excl; u[i] = excl; }
    __syncthreads();
    if (threadIdx.x == 0) carry_s += buf[1023];
    __syncthreads();
  }
  if (threadIdx.x == 0) o[n] = carry_s;
}

__global__ __launch_bounds__(256) void scatter_kernel(const int* __restrict__ ss,
                                                      const int* __restrict__ sd,
                                                      const int* __restrict__ rs,
                                                      const int* __restrict__ rd,
                                                      int* __restrict__ cur_s,
                                                      int* __restrict__ cur_ru,
                                                      int* __restrict__ cur_v,
                                                      int* __restrict__ idx_s,
                                                      int* __restrict__ idx_ru,
                                                      int* __restrict__ idx_v) {
  int stride = gridDim.x * 256;
  for (int e = blockIdx.x * 256 + threadIdx.x; e < ER; e += stride) {
    if (e < ES) {
      int p = atomicAdd(&cur_s[sd[e]], 1);
      idx_s[p] = ss[e];
    }
    int s = rs[e], d = rd[e];
    int p = atomicAdd(&cur_ru[s], 1);
    idx_ru[p] = d;
    int q = atomicAdd(&cur_v[d], 1);
    idx_v[q] = s;
  }
}

__global__ __launch_bounds__(256) void gmean_kernel(const float* __restrict__ tab,
                                                    const int* __restrict__ off,
                                                    const int* __restrict__ idx, int N,
                                                    float* __restrict__ mean) {
  int wid = (blockIdx.x * 256 + threadIdx.x) >> 6;
  int lane = threadIdx.x & 63;
  if (wid >= N) return;
  int b = off[wid], e = off[wid + 1];
  float acc0 = 0.0f, acc1 = 0.0f, acc2 = 0.0f, acc3 = 0.0f;
  int i = b;
  for (; i + 3 < e; i += 4) {
    int n0 = idx[i], n1 = idx[i + 1], n2 = idx[i + 2], n3 = idx[i + 3];
    acc0 += tab[(size_t)n0 * 64 + lane];
    acc1 += tab[(size_t)n1 * 64 + lane];
    acc2 += tab[(size_t)n2 * 64 + lane];
    acc3 += tab[(size_t)n3 * 64 + lane];
  }
  for (; i < e; ++i) acc0 += tab[(size_t)idx[i] * 64 + lane];
  float acc = (acc0 + acc1) + (acc2 + acc3);
  float inv = (e > b) ? 1.0f / (float)(e - b) : 0.0f;
  mean[(size_t)wid * 64 + lane] = acc * inv;
}

__global__ __launch_bounds__(256) void hu_kernel(const float* __restrict__ u2e,
                                                 const float* __restrict__ wcomb,
                                                 const float* __restrict__ W_neigh,
                                                 const float* __restrict__ mean_soc,
                                                 const float* __restrict__ mean_ru,
                                                 float* __restrict__ h_u) {
  __shared__ float Wc[4096], W0[4096], W2[4096], bc[64];
  for (int i = threadIdx.x; i < 4096; i += 256) {
    Wc[i] = wcomb[i];
    W0[i] = W_neigh[i];
    W2[i] = W_neigh[8192 + i];
  }
  if (threadIdx.x < 64) bc[threadIdx.x] = wcomb[4096 + threadIdx.x];
  __syncthreads();
  int row = blockIdx.x * 256 + threadIdx.x;
  if (row >= NU) return;
  float4 acc[16];
#pragma unroll
  for (int j = 0; j < 16; ++j) acc[j] = ((const float4*)bc)[j];
  const float4* xr = (const float4*)&u2e[(size_t)row * 64];
  const float4* n0 = (const float4*)&mean_soc[(size_t)row * 64];
  const float4* n2 = (const float4*)&mean_ru[(size_t)row * 64];
#pragma unroll 1
  for (int k4 = 0; k4 < 16; ++k4) {
    float4 a = xr[k4], b0 = n0[k4], b2 = n2[k4];
#pragma unroll
    for (int kk = 0; kk < 4; ++kk) {
      int k = k4 * 4 + kk;
      fma_row((&a.x)[kk], &Wc[k * 64], acc);
      fma_row((&b0.x)[kk], &W0[k * 64], acc);
      fma_row((&b2.x)[kk], &W2[k * 64], acc);
    }
  }
  float4* o = (float4*)&h_u[(size_t)row * 64];
#pragma unroll
  for (int j = 0; j < 16; ++j) o[j] = acc[j];
}

__global__ __launch_bounds__(256) void hv_kernel(const float* __restrict__ v2e,
                                                 const float* __restrict__ W_self,
                                                 const float* __restrict__ b_self,
                                                 const float* __restrict__ W_neigh,
                                                 const float* __restrict__ mean_v,
                                                 float* __restrict__ h_v) {
  __shared__ float Ws[4096], Wn[4096], bl[64];
  for (int i = threadIdx.x; i < 4096; i += 256) {
    Ws[i] = W_self[4096 + i];
    Wn[i] = W_neigh[4096 + i];
  }
  if (threadIdx.x < 64) bl[threadIdx.x] = b_self[64 + threadIdx.x];
  __syncthreads();
  int row = blockIdx.x * 256 + threadIdx.x;
  if (row >= NV) return;
  float4 acc[16];
#pragma unroll
  for (int j = 0; j < 16; ++j) acc[j] = ((const float4*)bl)[j];
  const float4* xr = (const float4*)&v2e[(size_t)row * 64];
  const float4* nv = (const float4*)&mean_v[(size_t)row * 64];
#pragma unroll 1
  for (int k4 = 0; k4 < 16; ++k4) {
    float4 a = xr[k4], b0 = nv[k4];
#pragma unroll
    for (int kk = 0; kk < 4; ++kk) {
      int k = k4 * 4 + kk;
      fma_row((&a.x)[kk], &Ws[k * 64], acc);
      fma_row((&b0.x)[kk], &Wn[k * 64], acc);
    }
  }
  float4* o = (float4*)&h_v[(size_t)row * 64];
#pragma unroll
  for (int j = 0; j < 16; ++j) o[j] = acc[j];
}

// ---- lin_stats: thread-per-row, acc in NAMED float4 registers.
#define CSTAT(VAL, IDX) { \
  float s_ = valid ? (VAL) : 0.0f; float q_ = s_ * s_; \
  s_ += __shfl_down(s_, 32, 64); q_ += __shfl_down(q_, 32, 64); \
  s_ += __shfl_down(s_, 16, 64); q_ += __shfl_down(q_, 16, 64); \
  s_ += __shfl_down(s_, 8, 64);  q_ += __shfl_down(q_, 8, 64); \
  s_ += __shfl_down(s_, 4, 64);  q_ += __shfl_down(q_, 4, 64); \
  s_ += __shfl_down(s_, 2, 64);  q_ += __shfl_down(q_, 2, 64); \
  s_ += __shfl_down(s_, 1, 64);  q_ += __shfl_down(q_, 1, 64); \
  if ((threadIdx.x & 63) == 0) { atomicAdd(&s1[IDX], s_); atomicAdd(&s2[IDX], q_); } }

__global__ __launch_bounds__(256) void lin_stats_kernel(const float* __restrict__ in,
                                                        const float* __restrict__ W,
                                                        const float* __restrict__ b, int N,
                                                        float* __restrict__ out,
                                                        float* __restrict__ ssum,
                                                        float* __restrict__ ssq) {
  __shared__ float Wl[4096], bl[64], s1[64], s2[64];
  for (int i = threadIdx.x; i < 4096; i += 256) Wl[i] = W[i];
  if (threadIdx.x < 64) {
    bl[threadIdx.x] = b[threadIdx.x];
    s1[threadIdx.x] = 0.0f;
    s2[threadIdx.x] = 0.0f;
  }
  __syncthreads();
  int row = blockIdx.x * 256 + threadIdx.x;
  bool valid = row < N;
  const float4* bl4 = (const float4*)bl;
#define LS_DECL(I) float4 A##I;
  REP16(LS_DECL)
#define LS_INIT(I) A##I = bl4[I];
  REP16(LS_INIT)
  if (valid) {
    const float4* xr = (const float4*)&in[(size_t)row * 64];
#define LS_FMA(I) { float4 w_ = W4_[I]; \
    A##I.x = fmaf(z_, w_.x, A##I.x); A##I.y = fmaf(z_, w_.y, A##I.y); \
    A##I.z = fmaf(z_, w_.z, A##I.z); A##I.w = fmaf(z_, w_.w, A##I.w); }
#define LS_DOFMA(ZV, K) { float z_ = (ZV); const float4* W4_ = (const float4*)&Wl[(K) * 64]; REP16(LS_FMA) }
#pragma unroll
    for (int k4 = 0; k4 < 16; ++k4) {
      float4 xa = xr[k4];
      LS_DOFMA(xa.x, k4 * 4 + 0)
      LS_DOFMA(xa.y, k4 * 4 + 1)
      LS_DOFMA(xa.z, k4 * 4 + 2)
      LS_DOFMA(xa.w, k4 * 4 + 3)
    }
    float4* o4 = (float4*)&out[(size_t)row * 64];
#define LS_ST(I) o4[I] = A##I;
    REP16(LS_ST)
  }
#define LS_CST(I) CSTAT(A##I.x, 4 * (I) + 0) CSTAT(A##I.y, 4 * (I) + 1) \
                  CSTAT(A##I.z, 4 * (I) + 2) CSTAT(A##I.w, 4 * (I) + 3)
  REP16(LS_CST)
  __syncthreads();
  if (threadIdx.x < 64) {
    atomicAdd(&ssum[threadIdx.x], s1[threadIdx.x]);
    atomicAdd(&ssq[threadIdx.x], s2[threadIdx.x]);
  }
}

__global__ __launch_bounds__(256) void bn_final_kernel(const float* __restrict__ ssum,
                                                       const float* __restrict__ ssq,
                                                       const float* __restrict__ gamma,
                                                       const float* __restrict__ beta,
                                                       float n, int C, float* __restrict__ bnp) {
  int j = threadIdx.x;
  if (j >= C) return;
  float m = ssum[j] / n;
  float var = ssq[j] / n - m * m;
  float s = gamma[j] * rsqrtf(var + EPS_BN);
  bnp[j] = s;
  bnp[C + j] = beta[j] - m * s;
}

__global__ __launch_bounds__(256) void bnrelu_lin_kernel(const float* __restrict__ tin,
                                                         const float* __restrict__ bnp,
                                                         const float* __restrict__ W,
                                                         const float* __restrict__ b, int N,
                                                         float* __restrict__ xout) {
  __shared__ float Wl[4096], bl[64], sc[64], sh[64];
  for (int i = threadIdx.x; i < 4096; i += 256) Wl[i] = W[i];
  if (threadIdx.x < 64) {
    bl[threadIdx.x] = b[threadIdx.x];
    sc[threadIdx.x] = bnp[threadIdx.x];
    sh[threadIdx.x] = bnp[64 + threadIdx.x];
  }
  __syncthreads();
  int row = blockIdx.x * 256 + threadIdx.x;
  if (row >= N) return;
  float4 acc[16];
#pragma unroll
  for (int j = 0; j < 16; ++j) acc[j] = ((const float4*)bl)[j];
  const float4* xr = (const float4*)&tin[(size_t)row * 64];
#pragma unroll 1
  for (int k4 = 0; k4 < 16; ++k4) {
    float4 a = xr[k4];
#pragma unroll
    for (int kk = 0; kk < 4; ++kk) {
      int k = k4 * 4 + kk;
      float z = fmaxf(fmaf((&a.x)[kk], sc[k], sh[k]), 0.0f);
      fma_row(z, &Wl[k * 64], acc);
    }
  }
  float4* o = (float4*)&xout[(size_t)row * 64];
#pragma unroll
  for (int j = 0; j < 16; ++j) o[j] = acc[j];
}

// ---- e1 v3: MFMA. Per 64-edge tile: P(64e x 64k) @ W(64k x 64j) via
// mfma_f32_16x16x32_bf16, double-bf16 (hi/lo) for fp32-equivalent precision.
// LDS P tiles XOR-swizzled (T2); wave w owns j-strip [16w,16w+16); C/D layout:
// col=lane&15 (j), row=(lane>>4)*4+reg (edge) [m89-verified].
__global__ __launch_bounds__(256) void e1_kernel(const float* __restrict__ xu,
                                                 const float* __restrict__ xv,
                                                 const int* __restrict__ rs,
                                                 const int* __restrict__ rd,
                                                 const float* __restrict__ W,
                                                 const float* __restrict__ b,
                                                 unsigned short* __restrict__ y1T,
                                                 float* __restrict__ ssum,
                                                 float* __restrict__ ssq) {
  __shared__ __attribute__((aligned(16))) unsigned short Phi[4096];  // [64e][64k] swizzled
  __shared__ __attribute__((aligned(16))) unsigned short Plo[4096];
  __shared__ __attribute__((aligned(16))) unsigned short Yt[64 * 66];  // [64j][66e-pad]
  const int lane = threadIdx.x & 63;
  const int wave = threadIdx.x >> 6;     // 0..3
  const int l15 = lane & 15;
  const int lhi = lane >> 4;             // 0..3
  const int j = wave * 16 + l15;         // this lane's output column

  // W fragments: B[k][j], lane holds k = ks*32 + lhi*8 + i (i=0..7), bf16 hi/lo
  bf16x8 Whi0, Wlo0, Whi1, Wlo1;
#pragma unroll
  for (int i = 0; i < 8; ++i) {
    {
      float w = W[(0 * 32 + lhi * 8 + i) * 64 + j];
      unsigned short h = f2bf(w);
      Whi0[i] = (short)h;
      Wlo0[i] = (short)f2bf(w - bf2f(h));
    }
    {
      float w = W[(1 * 32 + lhi * 8 + i) * 64 + j];
      unsigned short h = f2bf(w);
      Whi1[i] = (short)h;
      Wlo1[i] = (short)f2bf(w - bf2f(h));
    }
  }
  float bj = b[j];
  float ssl = 0.0f, sql = 0.0f;
  f32x4 acc0, acc1, acc2, acc3;
  const int ntiles = ER / 64;   // 15625 exactly
  for (int t = blockIdx.x; t < ntiles; t += gridDim.x) {
    int e0 = t * 64;
    // phase 1: gather + mul this wave's 16 edges; split to bf16 hi/lo in swizzled LDS
#pragma unroll 4
    for (int i = 0; i < 16; ++i) {
      int el = wave * 16 + i;
      int e = e0 + el;
      float p = xu[(size_t)rs[e] * 64 + lane] * xv[(size_t)rd[e] * 64 + lane];
      unsigned short ph = f2bf(p);
      unsigned short pl = f2bf(p - bf2f(ph));
      int idx = (el * 64 + lane) ^ ((el & 7) << 3);
      Phi[idx] = ph;
      Plo[idx] = pl;
    }
    __syncthreads();
    // MFMA phase: this wave's 16-column strip over all 64 edges
    acc0.x = bj; acc0.y = bj; acc0.z = bj; acc0.w = bj;
    acc1 = acc0; acc2 = acc0; acc3 = acc0;
#define E1_MM(MT, KS, WH, WL) { \
      int row_ = (MT) * 16 + l15; \
      int idx_ = (row_ * 64 + (KS) * 32 + lhi * 8) ^ ((row_ & 7) << 3); \
      bf16x8 ah_ = *(const bf16x8*)&Phi[idx_]; \
      bf16x8 al_ = *(const bf16x8*)&Plo[idx_]; \
      acc##MT = __builtin_amdgcn_mfma_f32_16x16x32_bf16(ah_, WH, acc##MT, 0, 0, 0); \
      acc##MT = __builtin_amdgcn_mfma_f32_16x16x32_bf16(al_, WH, acc##MT, 0, 0, 0); \
      acc##MT = __builtin_amdgcn_mfma_f32_16x16x32_bf16(ah_, WL, acc##MT, 0, 0, 0); }
    E1_MM(0, 0, Whi0, Wlo0) E1_MM(1, 0, Whi0, Wlo0) E1_MM(2, 0, Whi0, Wlo0) E1_MM(3, 0, Whi0, Wlo0)
    E1_MM(0, 1, Whi1, Wlo1) E1_MM(1, 1, Whi1, Wlo1) E1_MM(2, 1, Whi1, Wlo1) E1_MM(3, 1, Whi1, Wlo1)
    // epilogue: stats in regs + pack bf16 pairs into wave-local Yt strip
#define E1_EP(MT) { \
      ssl += (acc##MT.x + acc##MT.y) + (acc##MT.z + acc##MT.w); \
      sql = fmaf(acc##MT.x, acc##MT.x, sql); \
      sql = fmaf(acc##MT.y, acc##MT.y, sql); \
      sql = fmaf(acc##MT.z, acc##MT.z, sql); \
      sql = fmaf(acc##MT.w, acc##MT.w, sql); \
      int eb_ = (MT) * 16 + lhi * 4; \
      unsigned v01_ = (unsigned)f2bf(acc##MT.x) | ((unsigned)f2bf(acc##MT.y) << 16); \
      unsigned v23_ = (unsigned)f2bf(acc##MT.z) | ((unsigned)f2bf(acc##MT.w) << 16); \
      *(unsigned*)&Yt[j * 66 + eb_] = v01_; \
      *(unsigned*)&Yt[j * 66 + eb_ + 2] = v23_; }
    REP4(E1_EP)
    // phase 3: coalesced NT write of own strip (wave-local Yt -> no extra barrier)
#pragma unroll 4
    for (int i = 0; i < 16; ++i) {
      int jj = wave * 16 + i;
      __builtin_nontemporal_store(Yt[jj * 66 + lane], &y1T[(size_t)jj * ER + e0 + lane]);
    }
    __syncthreads();   // P tiles reusable next iteration
  }
  // stats: lanes {l, l+16, l+32, l+48} share column j
  ssl += __shfl_down(ssl, 32, 64);
  sql += __shfl_down(sql, 32, 64);
  ssl += __shfl_down(ssl, 16, 64);
  sql += __shfl_down(sql, 16, 64);
  if (lhi == 0) {
    atomicAdd(&ssum[j], ssl);
    atomicAdd(&ssq[j], sql);
  }
}

// ---- e2: thread-per-edge on column-major y1T, NAMED register accumulators.
#define ESTAT(SV, QV, IDX) { \
  float s_ = (SV); float q_ = (QV); \
  s_ += __shfl_down(s_, 32, 64); q_ += __shfl_down(q_, 32, 64); \
  s_ += __shfl_down(s_, 16, 64); q_ += __shfl_down(q_, 16, 64); \
  s_ += __shfl_down(s_, 8, 64);  q_ += __shfl_down(q_, 8, 64); \
  s_ += __shfl_down(s_, 4, 64);  q_ += __shfl_down(q_, 4, 64); \
  s_ += __shfl_down(s_, 2, 64);  q_ += __shfl_down(q_, 2, 64); \
  s_ += __shfl_down(s_, 1, 64);  q_ += __shfl_down(q_, 1, 64); \
  if ((threadIdx.x & 63) == 0) { atomicAdd(&s1[IDX], s_); atomicAdd(&s2[IDX], q_); } }

__global__ __launch_bounds__(256) void e2_kernel(const unsigned short* __restrict__ y1T,
                                                 const float* __restrict__ bnp3,
                                                 const float* __restrict__ W,   // [64,16]
                                                 const float* __restrict__ b,   // [16]
                                                 unsigned short* __restrict__ y2T,
                                                 float* __restrict__ ssum,
                                                 float* __restrict__ ssq) {
  __shared__ float Wl[1024], bl[16], sc[64], sh[64], s1[16], s2[16];
  for (int i = threadIdx.x; i < 1024; i += 256) Wl[i] = W[i];
  if (threadIdx.x < 16) {
    bl[threadIdx.x] = b[threadIdx.x];
    s1[threadIdx.x] = 0.0f;
    s2[threadIdx.x] = 0.0f;
  }
  if (threadIdx.x < 64) { sc[threadIdx.x] = bnp3[threadIdx.x]; sh[threadIdx.x] = bnp3[64 + threadIdx.x]; }
  __syncthreads();
  const float4* bl4 = (const float4*)bl;
  const float4* Wl4 = (const float4*)Wl;
#define E2_DECL(I) float4 B##I; \
  float4 SA##I = make_float4(0.f, 0.f, 0.f, 0.f); \
  float4 SQ##I = make_float4(0.f, 0.f, 0.f, 0.f);
  REP4(E2_DECL)
  int stride = gridDim.x * 256;
  for (int e = blockIdx.x * 256 + threadIdx.x; e < ER; e += stride) {
#define E2_INIT(I) B##I = bl4[I];
    REP4(E2_INIT)
#pragma unroll 4
    for (int k = 0; k < 64; ++k) {
      unsigned short yv = __builtin_nontemporal_load(&y1T[(size_t)k * ER + e]);
      float z = fmaxf(fmaf(bf2f(yv), sc[k], sh[k]), 0.0f);
#define E2_FMA(I) { float4 w_ = Wl4[(k << 2) + (I)]; \
      B##I.x = fmaf(z, w_.x, B##I.x); B##I.y = fmaf(z, w_.y, B##I.y); \
      B##I.z = fmaf(z, w_.z, B##I.z); B##I.w = fmaf(z, w_.w, B##I.w); }
      REP4(E2_FMA)
    }
#define E2_OUT(I) \
    __builtin_nontemporal_store(f2bf(B##I.x), &y2T[(size_t)(4 * (I) + 0) * ER + e]); SA##I.x += B##I.x; SQ##I.x = fmaf(B##I.x, B##I.x, SQ##I.x); \
    __builtin_nontemporal_store(f2bf(B##I.y), &y2T[(size_t)(4 * (I) + 1) * ER + e]); SA##I.y += B##I.y; SQ##I.y = fmaf(B##I.y, B##I.y, SQ##I.y); \
    __builtin_nontemporal_store(f2bf(B##I.z), &y2T[(size_t)(4 * (I) + 2) * ER + e]); SA##I.z += B##I.z; SQ##I.z = fmaf(B##I.z, B##I.z, SQ##I.z); \
    __builtin_nontemporal_store(f2bf(B##I.w), &y2T[(size_t)(4 * (I) + 3) * ER + e]); SA##I.w += B##I.w; SQ##I.w = fmaf(B##I.w, B##I.w, SQ##I.w);
    REP4(E2_OUT)
  }
#define E2_RED(I) ESTAT(SA##I.x, SQ##I.x, 4 * (I) + 0) ESTAT(SA##I.y, SQ##I.y, 4 * (I) + 1) \
                  ESTAT(SA##I.z, SQ##I.z, 4 * (I) + 2) ESTAT(SA##I.w, SQ##I.w, 4 * (I) + 3)
  REP4(E2_RED)
  __syncthreads();
  if (threadIdx.x < 16) {
    atomicAdd(&ssum[threadIdx.x], s1[threadIdx.x]);
    atomicAdd(&ssq[threadIdx.x], s2[threadIdx.x]);
  }
}

__global__ __launch_bounds__(256) void e3_kernel(const unsigned short* __restrict__ y2T,
                                                 const float* __restrict__ bnp4,
                                                 const float* __restrict__ w3,
                                                 const float* __restrict__ b3,
                                                 float* __restrict__ out) {
  __shared__ float sc[16], sh[16], wl[16];
  if (threadIdx.x < 16) {
    sc[threadIdx.x] = bnp4[threadIdx.x];
    sh[threadIdx.x] = bnp4[16 + threadIdx.x];
    wl[threadIdx.x] = w3[threadIdx.x];
  }
  __syncthreads();
  int e = blockIdx.x * 256 + threadIdx.x;
  if (e >= ER) return;
  float acc = b3[0];
#pragma unroll
  for (int j = 0; j < 16; ++j) {
    unsigned short yv = __builtin_nontemporal_load(&y2T[(size_t)j * ER + e]);
    float z = fmaxf(fmaf(bf2f(yv), sc[j], sh[j]), 0.0f);
    acc = fmaf(z, wl[j], acc);
  }
  out[e] = acc;
}

// ---------------- host ----------------
extern "C" void kernel_launch(void* const* d_in, const int* in_sizes, int n_in,
                              void* d_out, int out_size, void* d_ws, size_t ws_size,
                              hipStream_t stream) {
  const float* u2e = (const float*)d_in[0];
  const float* v2e = (const float*)d_in[1];
  const float* W_self = (const float*)d_in[2];
  const float* b_self = (const float*)d_in[3];
  const float* W_neigh = (const float*)d_in[4];
  const float* Wur1 = (const float*)d_in[5];
  const float* bur1 = (const float*)d_in[6];
  const float* Wur2 = (const float*)d_in[7];
  const float* bur2 = (const float*)d_in[8];
  const float* Wvr1 = (const float*)d_in[9];
  const float* bvr1 = (const float*)d_in[10];
  const float* Wvr2 = (const float*)d_in[11];
  const float* bvr2 = (const float*)d_in[12];
  const float* Wuv1 = (const float*)d_in[13];
  const float* buv1 = (const float*)d_in[14];
  const float* Wuv2 = (const float*)d_in[15];
  const float* buv2 = (const float*)d_in[16];
  const float* Wuv3 = (const float*)d_in[17];
  const float* buv3 = (const float*)d_in[18];
  const float* bn_gamma = (const float*)d_in[19];
  const float* bn_beta = (const float*)d_in[20];
  const float* bn4_gamma = (const float*)d_in[21];
  const float* bn4_beta = (const float*)d_in[22];
  const int* social_src = (const int*)d_in[23];
  const int* social_dst = (const int*)d_in[24];
  const int* rates_src = (const int*)d_in[25];
  const int* rates_dst = (const int*)d_in[26];
  float* out = (float*)d_out;
  float* ws = (float*)d_ws;

  float* A = ws + OFF_A;
  float* Cb = ws + OFF_C;
  float* Db = ws + OFF_D;
  float* Eb = ws + OFF_E;
  float* Fb = ws + OFF_F;
  float* wcomb = ws + OFF_WCOMB;
  float* stats = ws + OFF_STATS;
  float* bnp = ws + OFF_BNP;
  char* y1base = (char*)d_ws + OFF_Y1_BYTES;
  int* idx_s  = (int*)(y1base + CSR_IDX_S);
  int* idx_ru = (int*)(y1base + CSR_IDX_RU);
  int* idx_v  = (int*)(y1base + CSR_IDX_V);
  int* cnt_s  = (int*)(y1base + CSR_CNT_S);
  int* cnt_ru = (int*)(y1base + CSR_CNT_RU);
  int* cnt_v  = (int*)(y1base + CSR_CNT_V);
  int* cur_s  = (int*)(y1base + CSR_CUR_S);
  int* cur_ru = (int*)(y1base + CSR_CUR_RU);
  int* cur_v  = (int*)(y1base + CSR_CUR_V);
  int* off_s  = (int*)(y1base + CSR_OFF_S);
  int* off_ru = (int*)(y1base + CSR_OFF_RU);
  int* off_v  = (int*)(y1base + CSR_OFF_V);
  unsigned short* y1T = (unsigned short*)y1base;
  unsigned short* y2T = (unsigned short*)((char*)d_ws + OFF_Y2_BYTES);

  hipMemsetAsync(cnt_s, 0, 3 * (size_t)NU * sizeof(int), stream);
  hipMemsetAsync(stats, 0, 464 * sizeof(float), stream);

  wcomb_kernel<<<16, 256, 0, stream>>>(W_self, b_self, wcomb);

  hist_kernel<<<2048, 256, 0, stream>>>(social_dst, rates_src, rates_dst, cnt_s, cnt_ru, cnt_v);
  scan3_kernel<<<3, 1024, 0, stream>>>(cnt_s, NU, off_s, cur_s,
                                       cnt_ru, NU, off_ru, cur_ru,
                                       cnt_v, NV, off_v, cur_v);
  scatter_kernel<<<2048, 256, 0, stream>>>(social_src, social_dst, rates_src, rates_dst,
                                           cur_s, cur_ru, cur_v, idx_s, idx_ru, idx_v);
  gmean_kernel<<<(NU * 64 + 255) / 256, 256, 0, stream>>>(u2e, off_s, idx_s, NU, A);
  gmean_kernel<<<(NU * 64 + 255) / 256, 256, 0, stream>>>(v2e, off_ru, idx_ru, NU, Cb);
  gmean_kernel<<<(NV * 64 + 255) / 256, 256, 0, stream>>>(u2e, off_v, idx_v, NV, Db);

  hu_kernel<<<(NU + 255) / 256, 256, 0, stream>>>(u2e, wcomb, W_neigh, A, Cb, Eb);
  hv_kernel<<<(NV + 255) / 256, 256, 0, stream>>>(v2e, W_self, b_self, W_neigh, Db, Fb);

  lin_stats_kernel<<<(NU + 255) / 256, 256, 0, stream>>>(Eb, Wur1, bur1, NU, A, stats + 0, stats + 64);
  lin_stats_kernel<<<(NV + 255) / 256, 256, 0, stream>>>(Fb, Wvr1, bvr1, NV, Cb, stats + 128, stats + 192);

  bn_final_kernel<<<1, 64, 0, stream>>>(stats + 0, stats + 64, bn_gamma, bn_beta, (float)NU, 64, bnp);
  bn_final_kernel<<<1, 64, 0, stream>>>(stats + 128, stats + 192, bn_gamma + 64, bn_beta + 64, (float)NV, 64, bnp + 128);

  bnrelu_lin_kernel<<<(NU + 255) / 256, 256, 0, stream>>>(A, bnp, Wur2, bur2, NU, Db);
  bnrelu_lin_kernel<<<(NV + 255) / 256, 256, 0, stream>>>(Cb, bnp + 128, Wvr2, bvr2, NV, Eb);

  e1_kernel<<<2048, 256, 0, stream>>>(Db, Eb, rates_src, rates_dst, Wuv1, buv1, y1T,
                                      stats + 256, stats + 320);
  bn_final_kernel<<<1, 64, 0, stream>>>(stats + 256, stats + 320, bn_gamma + 128, bn_beta + 128,
                                        (float)ER, 64, bnp + 256);
  e2_kernel<<<2048, 256, 0, stream>>>(y1T, bnp + 256, Wuv2, buv2, y2T,
                                      stats + 384, stats + 400);
  bn_final_kernel<<<1, 16, 0, stream>>>(stats + 384, stats + 400, bn4_gamma, bn4_beta,
                                        (float)ER, 16, bnp + 384);
  e3_kernel<<<(ER + 255) / 256, 256, 0, stream>>>(y2T, bnp + 384, Wuv3, buv3, out);
}

// Round 9
// 1138.547 us; speedup vs baseline: 2.0591x; 1.0057x over previous
//
#include <hip/hip_runtime.h>

#define NU 50000
#define NV 50000
#define ES 800000
#define ER 1000000
#define EPS_BN 1e-5f

// ---------------- workspace layout ----------------
// floats:
static const size_t OFF_A       = 0;         // mean_soc -> t_u
static const size_t OFF_C       = 3350000;   // mean_ru -> t_v
static const size_t OFF_D       = 6550000;   // mean_v  -> x_u
static const size_t OFF_E       = 9750000;   // h_u     -> x_v
static const size_t OFF_F       = 12950000;  // h_v
static const size_t OFF_WCOMB   = 16150000;
static const size_t OFF_STATS   = 16154160;
static const size_t OFF_BNP     = 16154624;
// bytes:
static const size_t OFF_Y1_BYTES = 64640000;   // y1T: [64][ER] bf16, 128MB (CSR scratch pre-e1)
static const size_t OFF_Y2_BYTES = 192640000;  // y2T: [16][ER] bf16, 32MB
// CSR scratch inside y1 region (byte offsets rel. to OFF_Y1_BYTES), consumed before e1.
// idx arrays are uint16 (node ids < 50000 < 65536).
static const size_t CSR_IDX_S  = 0;          // ES u16
static const size_t CSR_IDX_RU = 3200000;    // ER u16
static const size_t CSR_IDX_V  = 7200000;    // ER u16
static const size_t CSR_CNT_S  = 11200000;
static const size_t CSR_CNT_RU = 11400000;
static const size_t CSR_CNT_V  = 11600000;
static const size_t CSR_CUR_S  = 11800000;
static const size_t CSR_CUR_RU = 12000000;
static const size_t CSR_CUR_V  = 12200000;
static const size_t CSR_OFF_S  = 12400000;
static const size_t CSR_OFF_RU = 12600016;
static const size_t CSR_OFF_V  = 12800032;

#define REP16(M) M(0) M(1) M(2) M(3) M(4) M(5) M(6) M(7) M(8) M(9) M(10) M(11) M(12) M(13) M(14) M(15)
#define REP4(M) M(0) M(1) M(2) M(3)

typedef __attribute__((ext_vector_type(8))) short bf16x8;
typedef __attribute__((ext_vector_type(4))) float f32x4;

// ---------------- helpers ----------------
__device__ __forceinline__ unsigned short f2bf(float f) {
  unsigned u = __float_as_uint(f);
  unsigned r = u + 0x7FFF + ((u >> 16) & 1);   // RNE (finite values)
  return (unsigned short)(r >> 16);
}
__device__ __forceinline__ float bf2f(unsigned short h) {
  return __uint_as_float(((unsigned)h) << 16);
}

__device__ __forceinline__ void fma_row(float xk, const float* __restrict__ wrow, float4* acc) {
  const float4* w = (const float4*)wrow;
#pragma unroll
  for (int j = 0; j < 16; ++j) {
    float4 wv = w[j];
    acc[j].x = fmaf(xk, wv.x, acc[j].x);
    acc[j].y = fmaf(xk, wv.y, acc[j].y);
    acc[j].z = fmaf(xk, wv.z, acc[j].z);
    acc[j].w = fmaf(xk, wv.w, acc[j].w);
  }
}

// ---------------- kernels ----------------
__global__ __launch_bounds__(256) void wcomb_kernel(const float* __restrict__ W_self,
                                                    const float* __restrict__ b_self,
                                                    float* __restrict__ wcomb) {
  int i = blockIdx.x * 256 + threadIdx.x;
  if (i < 4096) wcomb[i] = W_self[i] + W_self[8192 + i];
  if (i < 64) wcomb[4096 + i] = b_self[i] + b_self[128 + i];
}

__global__ __launch_bounds__(256) void hist_kernel(const int* __restrict__ sd,
                                                   const int* __restrict__ rs,
                                                   const int* __restrict__ rd,
                                                   int* __restrict__ cnt_s,
                                                   int* __restrict__ cnt_ru,
                                                   int* __restrict__ cnt_v) {
  int stride = gridDim.x * 256;
  for (int e = blockIdx.x * 256 + threadIdx.x; e < ER; e += stride) {
    if (e < ES) atomicAdd(&cnt_s[sd[e]], 1);
    atomicAdd(&cnt_ru[rs[e]], 1);
    atomicAdd(&cnt_v[rd[e]], 1);
  }
}

// 3 blocks; per block: thread-serial chunk sums -> one 1024-wide LDS scan ->
// serial prefix write-out. Writes off[0..n] and cur[0..n-1]=off.
__global__ __launch_bounds__(1024) void scan3_kernel(const int* __restrict__ c0, int n0, int* o0, int* u0,
                                                     const int* __restrict__ c1, int n1, int* o1, int* u1,
                                                     const int* __restrict__ c2, int n2, int* o2, int* u2) {
  const int* c; int n; int* o; int* u;
  if (blockIdx.x == 0) { c = c0; n = n0; o = o0; u = u0; }
  else if (blockIdx.x == 1) { c = c1; n = n1; o = o1; u = u1; }
  else { c = c2; n = n2; o = o2; u = u2; }
  __shared__ int buf[1024];
  int t = threadIdx.x;
  int ch = (n + 1023) >> 10;
  int begin = t * ch;
  int end = begin + ch; if (end > n) end = n; if (begin > n) begin = n;
  int sum = 0;
  for (int i = begin; i < end; ++i) sum += c[i];
  buf[t] = sum;
  __syncthreads();
#pragma unroll
  for (int ofs = 1; ofs < 1024; ofs <<= 1) {
    int v = 0;
    if (t >= ofs) v = buf[t - ofs];
    __syncthreads();
    buf[t] += v;
    __syncthreads();
  }
  int run = buf[t] - sum;   // exclusive prefix of this chunk
  for (int i = begin; i < end; ++i) {
    int v = c[i];
    o[i] = run;
    u[i] = run;
    run += v;
  }
  if (t == 1023) o[n] = run;
}

// scatter edge endpoints into CSR slots (uint16 payloads)
__global__ __launch_bounds__(256) void scatter_kernel(const int* __restrict__ ss,
                                                      const int* __restrict__ sd,
                                                      const int* __restrict__ rs,
                                                      const int* __restrict__ rd,
                                                      int* __restrict__ cur_s,
                                                      int* __restrict__ cur_ru,
                                                      int* __restrict__ cur_v,
                                                      unsigned short* __restrict__ idx_s,
                                                      unsigned short* __restrict__ idx_ru,
                                                      unsigned short* __restrict__ idx_v) {
  int stride = gridDim.x * 256;
  for (int e = blockIdx.x * 256 + threadIdx.x; e < ER; e += stride) {
    if (e < ES) {
      int p = atomicAdd(&cur_s[sd[e]], 1);
      idx_s[p] = (unsigned short)ss[e];
    }
    int s = rs[e], d = rd[e];
    int p = atomicAdd(&cur_ru[s], 1);
    idx_ru[p] = (unsigned short)d;
    int q = atomicAdd(&cur_v[d], 1);
    idx_v[q] = (unsigned short)s;
  }
}

__global__ __launch_bounds__(256) void gmean_kernel(const float* __restrict__ tab,
                                                    const int* __restrict__ off,
                                                    const unsigned short* __restrict__ idx, int N,
                                                    float* __restrict__ mean) {
  int wid = (blockIdx.x * 256 + threadIdx.x) >> 6;
  int lane = threadIdx.x & 63;
  if (wid >= N) return;
  int b = off[wid], e = off[wid + 1];
  float acc0 = 0.0f, acc1 = 0.0f, acc2 = 0.0f, acc3 = 0.0f;
  int i = b;
  for (; i + 3 < e; i += 4) {
    int n0 = idx[i], n1 = idx[i + 1], n2 = idx[i + 2], n3 = idx[i + 3];
    acc0 += tab[(size_t)n0 * 64 + lane];
    acc1 += tab[(size_t)n1 * 64 + lane];
    acc2 += tab[(size_t)n2 * 64 + lane];
    acc3 += tab[(size_t)n3 * 64 + lane];
  }
  for (; i < e; ++i) acc0 += tab[(size_t)idx[i] * 64 + lane];
  float acc = (acc0 + acc1) + (acc2 + acc3);
  float inv = (e > b) ? 1.0f / (float)(e - b) : 0.0f;
  mean[(size_t)wid * 64 + lane] = acc * inv;
}

__global__ __launch_bounds__(256) void hu_kernel(const float* __restrict__ u2e,
                                                 const float* __restrict__ wcomb,
                                                 const float* __restrict__ W_neigh,
                                                 const float* __restrict__ mean_soc,
                                                 const float* __restrict__ mean_ru,
                                                 float* __restrict__ h_u) {
  __shared__ float Wc[4096], W0[4096], W2[4096], bc[64];
  for (int i = threadIdx.x; i < 4096; i += 256) {
    Wc[i] = wcomb[i];
    W0[i] = W_neigh[i];
    W2[i] = W_neigh[8192 + i];
  }
  if (threadIdx.x < 64) bc[threadIdx.x] = wcomb[4096 + threadIdx.x];
  __syncthreads();
  int row = blockIdx.x * 256 + threadIdx.x;
  if (row >= NU) return;
  float4 acc[16];
#pragma unroll
  for (int j = 0; j < 16; ++j) acc[j] = ((const float4*)bc)[j];
  const float4* xr = (const float4*)&u2e[(size_t)row * 64];
  const float4* n0 = (const float4*)&mean_soc[(size_t)row * 64];
  const float4* n2 = (const float4*)&mean_ru[(size_t)row * 64];
#pragma unroll 1
  for (int k4 = 0; k4 < 16; ++k4) {
    float4 a = xr[k4], b0 = n0[k4], b2 = n2[k4];
#pragma unroll
    for (int kk = 0; kk < 4; ++kk) {
      int k = k4 * 4 + kk;
      fma_row((&a.x)[kk], &Wc[k * 64], acc);
      fma_row((&b0.x)[kk], &W0[k * 64], acc);
      fma_row((&b2.x)[kk], &W2[k * 64], acc);
    }
  }
  float4* o = (float4*)&h_u[(size_t)row * 64];
#pragma unroll
  for (int j = 0; j < 16; ++j) o[j] = acc[j];
}

__global__ __launch_bounds__(256) void hv_kernel(const float* __restrict__ v2e,
                                                 const float* __restrict__ W_self,
                                                 const float* __restrict__ b_self,
                                                 const float* __restrict__ W_neigh,
                                                 const float* __restrict__ mean_v,
                                                 float* __restrict__ h_v) {
  __shared__ float Ws[4096], Wn[4096], bl[64];
  for (int i = threadIdx.x; i < 4096; i += 256) {
    Ws[i] = W_self[4096 + i];
    Wn[i] = W_neigh[4096 + i];
  }
  if (threadIdx.x < 64) bl[threadIdx.x] = b_self[64 + threadIdx.x];
  __syncthreads();
  int row = blockIdx.x * 256 + threadIdx.x;
  if (row >= NV) return;
  float4 acc[16];
#pragma unroll
  for (int j = 0; j < 16; ++j) acc[j] = ((const float4*)bl)[j];
  const float4* xr = (const float4*)&v2e[(size_t)row * 64];
  const float4* nv = (const float4*)&mean_v[(size_t)row * 64];
#pragma unroll 1
  for (int k4 = 0; k4 < 16; ++k4) {
    float4 a = xr[k4], b0 = nv[k4];
#pragma unroll
    for (int kk = 0; kk < 4; ++kk) {
      int k = k4 * 4 + kk;
      fma_row((&a.x)[kk], &Ws[k * 64], acc);
      fma_row((&b0.x)[kk], &Wn[k * 64], acc);
    }
  }
  float4* o = (float4*)&h_v[(size_t)row * 64];
#pragma unroll
  for (int j = 0; j < 16; ++j) o[j] = acc[j];
}

// ---- lin_stats: thread-per-row, acc in NAMED float4 registers.
#define CSTAT(VAL, IDX) { \
  float s_ = valid ? (VAL) : 0.0f; float q_ = s_ * s_; \
  s_ += __shfl_down(s_, 32, 64); q_ += __shfl_down(q_, 32, 64); \
  s_ += __shfl_down(s_, 16, 64); q_ += __shfl_down(q_, 16, 64); \
  s_ += __shfl_down(s_, 8, 64);  q_ += __shfl_down(q_, 8, 64); \
  s_ += __shfl_down(s_, 4, 64);  q_ += __shfl_down(q_, 4, 64); \
  s_ += __shfl_down(s_, 2, 64);  q_ += __shfl_down(q_, 2, 64); \
  s_ += __shfl_down(s_, 1, 64);  q_ += __shfl_down(q_, 1, 64); \
  if ((threadIdx.x & 63) == 0) { atomicAdd(&s1[IDX], s_); atomicAdd(&s2[IDX], q_); } }

__global__ __launch_bounds__(256) void lin_stats_kernel(const float* __restrict__ in,
                                                        const float* __restrict__ W,
                                                        const float* __restrict__ b, int N,
                                                        float* __restrict__ out,
                                                        float* __restrict__ ssum,
                                                        float* __restrict__ ssq) {
  __shared__ float Wl[4096], bl[64], s1[64], s2[64];
  for (int i = threadIdx.x; i < 4096; i += 256) Wl[i] = W[i];
  if (threadIdx.x < 64) {
    bl[threadIdx.x] = b[threadIdx.x];
    s1[threadIdx.x] = 0.0f;
    s2[threadIdx.x] = 0.0f;
  }
  __syncthreads();
  int row = blockIdx.x * 256 + threadIdx.x;
  bool valid = row < N;
  const float4* bl4 = (const float4*)bl;
#define LS_DECL(I) float4 A##I;
  REP16(LS_DECL)
#define LS_INIT(I) A##I = bl4[I];
  REP16(LS_INIT)
  if (valid) {
    const float4* xr = (const float4*)&in[(size_t)row * 64];
#define LS_FMA(I) { float4 w_ = W4_[I]; \
    A##I.x = fmaf(z_, w_.x, A##I.x); A##I.y = fmaf(z_, w_.y, A##I.y); \
    A##I.z = fmaf(z_, w_.z, A##I.z); A##I.w = fmaf(z_, w_.w, A##I.w); }
#define LS_DOFMA(ZV, K) { float z_ = (ZV); const float4* W4_ = (const float4*)&Wl[(K) * 64]; REP16(LS_FMA) }
#pragma unroll
    for (int k4 = 0; k4 < 16; ++k4) {
      float4 xa = xr[k4];
      LS_DOFMA(xa.x, k4 * 4 + 0)
      LS_DOFMA(xa.y, k4 * 4 + 1)
      LS_DOFMA(xa.z, k4 * 4 + 2)
      LS_DOFMA(xa.w, k4 * 4 + 3)
    }
    float4* o4 = (float4*)&out[(size_t)row * 64];
#define LS_ST(I) o4[I] = A##I;
    REP16(LS_ST)
  }
#define LS_CST(I) CSTAT(A##I.x, 4 * (I) + 0) CSTAT(A##I.y, 4 * (I) + 1) \
                  CSTAT(A##I.z, 4 * (I) + 2) CSTAT(A##I.w, 4 * (I) + 3)
  REP16(LS_CST)
  __syncthreads();
  if (threadIdx.x < 64) {
    atomicAdd(&ssum[threadIdx.x], s1[threadIdx.x]);
    atomicAdd(&ssq[threadIdx.x], s2[threadIdx.x]);
  }
}

__global__ __launch_bounds__(256) void bn_final_kernel(const float* __restrict__ ssum,
                                                       const float* __restrict__ ssq,
                                                       const float* __restrict__ gamma,
                                                       const float* __restrict__ beta,
                                                       float n, int C, float* __restrict__ bnp) {
  int j = threadIdx.x;
  if (j >= C) return;
  float m = ssum[j] / n;
  float var = ssq[j] / n - m * m;
  float s = gamma[j] * rsqrtf(var + EPS_BN);
  bnp[j] = s;
  bnp[C + j] = beta[j] - m * s;
}

__global__ __launch_bounds__(256) void bnrelu_lin_kernel(const float* __restrict__ tin,
                                                         const float* __restrict__ bnp,
                                                         const float* __restrict__ W,
                                                         const float* __restrict__ b, int N,
                                                         float* __restrict__ xout) {
  __shared__ float Wl[4096], bl[64], sc[64], sh[64];
  for (int i = threadIdx.x; i < 4096; i += 256) Wl[i] = W[i];
  if (threadIdx.x < 64) {
    bl[threadIdx.x] = b[threadIdx.x];
    sc[threadIdx.x] = bnp[threadIdx.x];
    sh[threadIdx.x] = bnp[64 + threadIdx.x];
  }
  __syncthreads();
  int row = blockIdx.x * 256 + threadIdx.x;
  if (row >= N) return;
  float4 acc[16];
#pragma unroll
  for (int j = 0; j < 16; ++j) acc[j] = ((const float4*)bl)[j];
  const float4* xr = (const float4*)&tin[(size_t)row * 64];
#pragma unroll 1
  for (int k4 = 0; k4 < 16; ++k4) {
    float4 a = xr[k4];
#pragma unroll
    for (int kk = 0; kk < 4; ++kk) {
      int k = k4 * 4 + kk;
      float z = fmaxf(fmaf((&a.x)[kk], sc[k], sh[k]), 0.0f);
      fma_row(z, &Wl[k * 64], acc);
    }
  }
  float4* o = (float4*)&xout[(size_t)row * 64];
#pragma unroll
  for (int j = 0; j < 16; ++j) o[j] = acc[j];
}

// ---- e1 v3: MFMA. Per 64-edge tile: P(64e x 64k) @ W(64k x 64j) via
// mfma_f32_16x16x32_bf16, double-bf16 (hi/lo). C/D: col=lane&15, row=(lane>>4)*4+reg.
__global__ __launch_bounds__(256) void e1_kernel(const float* __restrict__ xu,
                                                 const float* __restrict__ xv,
                                                 const int* __restrict__ rs,
                                                 const int* __restrict__ rd,
                                                 const float* __restrict__ W,
                                                 const float* __restrict__ b,
                                                 unsigned short* __restrict__ y1T,
                                                 float* __restrict__ ssum,
                                                 float* __restrict__ ssq) {
  __shared__ __attribute__((aligned(16))) unsigned short Phi[4096];  // [64e][64k] swizzled
  __shared__ __attribute__((aligned(16))) unsigned short Plo[4096];
  __shared__ __attribute__((aligned(16))) unsigned short Yt[64 * 66];  // [64j][66e-pad]
  const int lane = threadIdx.x & 63;
  const int wave = threadIdx.x >> 6;     // 0..3
  const int l15 = lane & 15;
  const int lhi = lane >> 4;             // 0..3
  const int j = wave * 16 + l15;         // this lane's output column

  bf16x8 Whi0, Wlo0, Whi1, Wlo1;
#pragma unroll
  for (int i = 0; i < 8; ++i) {
    {
      float w = W[(0 * 32 + lhi * 8 + i) * 64 + j];
      unsigned short h = f2bf(w);
      Whi0[i] = (short)h;
      Wlo0[i] = (short)f2bf(w - bf2f(h));
    }
    {
      float w = W[(1 * 32 + lhi * 8 + i) * 64 + j];
      unsigned short h = f2bf(w);
      Whi1[i] = (short)h;
      Wlo1[i] = (short)f2bf(w - bf2f(h));
    }
  }
  float bj = b[j];
  float ssl = 0.0f, sql = 0.0f;
  f32x4 acc0, acc1, acc2, acc3;
  const int ntiles = ER / 64;   // 15625 exactly
  for (int t = blockIdx.x; t < ntiles; t += gridDim.x) {
    int e0 = t * 64;
#pragma unroll 4
    for (int i = 0; i < 16; ++i) {
      int el = wave * 16 + i;
      int e = e0 + el;
      float p = xu[(size_t)rs[e] * 64 + lane] * xv[(size_t)rd[e] * 64 + lane];
      unsigned short ph = f2bf(p);
      unsigned short pl = f2bf(p - bf2f(ph));
      int idx = (el * 64 + lane) ^ ((el & 7) << 3);
      Phi[idx] = ph;
      Plo[idx] = pl;
    }
    __syncthreads();
    acc0.x = bj; acc0.y = bj; acc0.z = bj; acc0.w = bj;
    acc1 = acc0; acc2 = acc0; acc3 = acc0;
#define E1_MM(MT, KS, WH, WL) { \
      int row_ = (MT) * 16 + l15; \
      int idx_ = (row_ * 64 + (KS) * 32 + lhi * 8) ^ ((row_ & 7) << 3); \
      bf16x8 ah_ = *(const bf16x8*)&Phi[idx_]; \
      bf16x8 al_ = *(const bf16x8*)&Plo[idx_]; \
      acc##MT = __builtin_amdgcn_mfma_f32_16x16x32_bf16(ah_, WH, acc##MT, 0, 0, 0); \
      acc##MT = __builtin_amdgcn_mfma_f32_16x16x32_bf16(al_, WH, acc##MT, 0, 0, 0); \
      acc##MT = __builtin_amdgcn_mfma_f32_16x16x32_bf16(ah_, WL, acc##MT, 0, 0, 0); }
    E1_MM(0, 0, Whi0, Wlo0) E1_MM(1, 0, Whi0, Wlo0) E1_MM(2, 0, Whi0, Wlo0) E1_MM(3, 0, Whi0, Wlo0)
    E1_MM(0, 1, Whi1, Wlo1) E1_MM(1, 1, Whi1, Wlo1) E1_MM(2, 1, Whi1, Wlo1) E1_MM(3, 1, Whi1, Wlo1)
#define E1_EP(MT) { \
      ssl += (acc##MT.x + acc##MT.y) + (acc##MT.z + acc##MT.w); \
      sql = fmaf(acc##MT.x, acc##MT.x, sql); \
      sql = fmaf(acc##MT.y, acc##MT.y, sql); \
      sql = fmaf(acc##MT.z, acc##MT.z, sql); \
      sql = fmaf(acc##MT.w, acc##MT.w, sql); \
      int eb_ = (MT) * 16 + lhi * 4; \
      unsigned v01_ = (unsigned)f2bf(acc##MT.x) | ((unsigned)f2bf(acc##MT.y) << 16); \
      unsigned v23_ = (unsigned)f2bf(acc##MT.z) | ((unsigned)f2bf(acc##MT.w) << 16); \
      *(unsigned*)&Yt[j * 66 + eb_] = v01_; \
      *(unsigned*)&Yt[j * 66 + eb_ + 2] = v23_; }
    REP4(E1_EP)
#pragma unroll 4
    for (int i = 0; i < 16; ++i) {
      int jj = wave * 16 + i;
      __builtin_nontemporal_store(Yt[jj * 66 + lane], &y1T[(size_t)jj * ER + e0 + lane]);
    }
    __syncthreads();
  }
  ssl += __shfl_down(ssl, 32, 64);
  sql += __shfl_down(sql, 32, 64);
  ssl += __shfl_down(ssl, 16, 64);
  sql += __shfl_down(sql, 16, 64);
  if (lhi == 0) {
    atomicAdd(&ssum[j], ssl);
    atomicAdd(&ssq[j], sql);
  }
}

// ---- e2: thread-per-edge on column-major y1T, NAMED register accumulators.
#define ESTAT(SV, QV, IDX) { \
  float s_ = (SV); float q_ = (QV); \
  s_ += __shfl_down(s_, 32, 64); q_ += __shfl_down(q_, 32, 64); \
  s_ += __shfl_down(s_, 16, 64); q_ += __shfl_down(q_, 16, 64); \
  s_ += __shfl_down(s_, 8, 64);  q_ += __shfl_down(q_, 8, 64); \
  s_ += __shfl_down(s_, 4, 64);  q_ += __shfl_down(q_, 4, 64); \
  s_ += __shfl_down(s_, 2, 64);  q_ += __shfl_down(q_, 2, 64); \
  s_ += __shfl_down(s_, 1, 64);  q_ += __shfl_down(q_, 1, 64); \
  if ((threadIdx.x & 63) == 0) { atomicAdd(&s1[IDX], s_); atomicAdd(&s2[IDX], q_); } }

__global__ __launch_bounds__(256) void e2_kernel(const unsigned short* __restrict__ y1T,
                                                 const float* __restrict__ bnp3,
                                                 const float* __restrict__ W,   // [64,16]
                                                 const float* __restrict__ b,   // [16]
                                                 unsigned short* __restrict__ y2T,
                                                 float* __restrict__ ssum,
                                                 float* __restrict__ ssq) {
  __shared__ float Wl[1024], bl[16], sc[64], sh[64], s1[16], s2[16];
  for (int i = threadIdx.x; i < 1024; i += 256) Wl[i] = W[i];
  if (threadIdx.x < 16) {
    bl[threadIdx.x] = b[threadIdx.x];
    s1[threadIdx.x] = 0.0f;
    s2[threadIdx.x] = 0.0f;
  }
  if (threadIdx.x < 64) { sc[threadIdx.x] = bnp3[threadIdx.x]; sh[threadIdx.x] = bnp3[64 + threadIdx.x]; }
  __syncthreads();
  const float4* bl4 = (const float4*)bl;
  const float4* Wl4 = (const float4*)Wl;
#define E2_DECL(I) float4 B##I; \
  float4 SA##I = make_float4(0.f, 0.f, 0.f, 0.f); \
  float4 SQ##I = make_float4(0.f, 0.f, 0.f, 0.f);
  REP4(E2_DECL)
  int stride = gridDim.x * 256;
  for (int e = blockIdx.x * 256 + threadIdx.x; e < ER; e += stride) {
#define E2_INIT(I) B##I = bl4[I];
    REP4(E2_INIT)
#pragma unroll 4
    for (int k = 0; k < 64; ++k) {
      unsigned short yv = __builtin_nontemporal_load(&y1T[(size_t)k * ER + e]);
      float z = fmaxf(fmaf(bf2f(yv), sc[k], sh[k]), 0.0f);
#define E2_FMA(I) { float4 w_ = Wl4[(k << 2) + (I)]; \
      B##I.x = fmaf(z, w_.x, B##I.x); B##I.y = fmaf(z, w_.y, B##I.y); \
      B##I.z = fmaf(z, w_.z, B##I.z); B##I.w = fmaf(z, w_.w, B##I.w); }
      REP4(E2_FMA)
    }
#define E2_OUT(I) \
    __builtin_nontemporal_store(f2bf(B##I.x), &y2T[(size_t)(4 * (I) + 0) * ER + e]); SA##I.x += B##I.x; SQ##I.x = fmaf(B##I.x, B##I.x, SQ##I.x); \
    __builtin_nontemporal_store(f2bf(B##I.y), &y2T[(size_t)(4 * (I) + 1) * ER + e]); SA##I.y += B##I.y; SQ##I.y = fmaf(B##I.y, B##I.y, SQ##I.y); \
    __builtin_nontemporal_store(f2bf(B##I.z), &y2T[(size_t)(4 * (I) + 2) * ER + e]); SA##I.z += B##I.z; SQ##I.z = fmaf(B##I.z, B##I.z, SQ##I.z); \
    __builtin_nontemporal_store(f2bf(B##I.w), &y2T[(size_t)(4 * (I) + 3) * ER + e]); SA##I.w += B##I.w; SQ##I.w = fmaf(B##I.w, B##I.w, SQ##I.w);
    REP4(E2_OUT)
  }
#define E2_RED(I) ESTAT(SA##I.x, SQ##I.x, 4 * (I) + 0) ESTAT(SA##I.y, SQ##I.y, 4 * (I) + 1) \
                  ESTAT(SA##I.z, SQ##I.z, 4 * (I) + 2) ESTAT(SA##I.w, SQ##I.w, 4 * (I) + 3)
  REP4(E2_RED)
  __syncthreads();
  if (threadIdx.x < 16) {
    atomicAdd(&ssum[threadIdx.x], s1[threadIdx.x]);
    atomicAdd(&ssq[threadIdx.x], s2[threadIdx.x]);
  }
}

__global__ __launch_bounds__(256) void e3_kernel(const unsigned short* __restrict__ y2T,
                                                 const float* __restrict__ bnp4,
                                                 const float* __restrict__ w3,
                                                 const float* __restrict__ b3,
                                                 float* __restrict__ out) {
  __shared__ float sc[16], sh[16], wl[16];
  if (threadIdx.x < 16) {
    sc[threadIdx.x] = bnp4[threadIdx.x];
    sh[threadIdx.x] = bnp4[16 + threadIdx.x];
    wl[threadIdx.x] = w3[threadIdx.x];
  }
  __syncthreads();
  int e = blockIdx.x * 256 + threadIdx.x;
  if (e >= ER) return;
  float acc = b3[0];
#pragma unroll
  for (int j = 0; j < 16; ++j) {
    unsigned short yv = __builtin_nontemporal_load(&y2T[(size_t)j * ER + e]);
    float z = fmaxf(fmaf(bf2f(yv), sc[j], sh[j]), 0.0f);
    acc = fmaf(z, wl[j], acc);
  }
  out[e] = acc;
}

// ---------------- host ----------------
extern "C" void kernel_launch(void* const* d_in, const int* in_sizes, int n_in,
                              void* d_out, int out_size, void* d_ws, size_t ws_size,
                              hipStream_t stream) {
  const float* u2e = (const float*)d_in[0];
  const float* v2e = (const float*)d_in[1];
  const float* W_self = (const float*)d_in[2];
  const float* b_self = (const float*)d_in[3];
  const float* W_neigh = (const float*)d_in[4];
  const float* Wur1 = (const float*)d_in[5];
  const float* bur1 = (const float*)d_in[6];
  const float* Wur2 = (const float*)d_in[7];
  const float* bur2 = (const float*)d_in[8];
  const float* Wvr1 = (const float*)d_in[9];
  const float* bvr1 = (const float*)d_in[10];
  const float* Wvr2 = (const float*)d_in[11];
  const float* bvr2 = (const float*)d_in[12];
  const float* Wuv1 = (const float*)d_in[13];
  const float* buv1 = (const float*)d_in[14];
  const float* Wuv2 = (const float*)d_in[15];
  const float* buv2 = (const float*)d_in[16];
  const float* Wuv3 = (const float*)d_in[17];
  const float* buv3 = (const float*)d_in[18];
  const float* bn_gamma = (const float*)d_in[19];
  const float* bn_beta = (const float*)d_in[20];
  const float* bn4_gamma = (const float*)d_in[21];
  const float* bn4_beta = (const float*)d_in[22];
  const int* social_src = (const int*)d_in[23];
  const int* social_dst = (const int*)d_in[24];
  const int* rates_src = (const int*)d_in[25];
  const int* rates_dst = (const int*)d_in[26];
  float* out = (float*)d_out;
  float* ws = (float*)d_ws;

  float* A = ws + OFF_A;
  float* Cb = ws + OFF_C;
  float* Db = ws + OFF_D;
  float* Eb = ws + OFF_E;
  float* Fb = ws + OFF_F;
  float* wcomb = ws + OFF_WCOMB;
  float* stats = ws + OFF_STATS;
  float* bnp = ws + OFF_BNP;
  char* y1base = (char*)d_ws + OFF_Y1_BYTES;
  unsigned short* idx_s  = (unsigned short*)(y1base + CSR_IDX_S);
  unsigned short* idx_ru = (unsigned short*)(y1base + CSR_IDX_RU);
  unsigned short* idx_v  = (unsigned short*)(y1base + CSR_IDX_V);
  int* cnt_s  = (int*)(y1base + CSR_CNT_S);
  int* cnt_ru = (int*)(y1base + CSR_CNT_RU);
  int* cnt_v  = (int*)(y1base + CSR_CNT_V);
  int* cur_s  = (int*)(y1base + CSR_CUR_S);
  int* cur_ru = (int*)(y1base + CSR_CUR_RU);
  int* cur_v  = (int*)(y1base + CSR_CUR_V);
  int* off_s  = (int*)(y1base + CSR_OFF_S);
  int* off_ru = (int*)(y1base + CSR_OFF_RU);
  int* off_v  = (int*)(y1base + CSR_OFF_V);
  unsigned short* y1T = (unsigned short*)y1base;
  unsigned short* y2T = (unsigned short*)((char*)d_ws + OFF_Y2_BYTES);

  hipMemsetAsync(cnt_s, 0, 3 * (size_t)NU * sizeof(int), stream);
  hipMemsetAsync(stats, 0, 464 * sizeof(float), stream);

  wcomb_kernel<<<16, 256, 0, stream>>>(W_self, b_self, wcomb);

  hist_kernel<<<2048, 256, 0, stream>>>(social_dst, rates_src, rates_dst, cnt_s, cnt_ru, cnt_v);
  scan3_kernel<<<3, 1024, 0, stream>>>(cnt_s, NU, off_s, cur_s,
                                       cnt_ru, NU, off_ru, cur_ru,
                                       cnt_v, NV, off_v, cur_v);
  scatter_kernel<<<2048, 256, 0, stream>>>(social_src, social_dst, rates_src, rates_dst,
                                           cur_s, cur_ru, cur_v, idx_s, idx_ru, idx_v);
  gmean_kernel<<<(NU * 64 + 255) / 256, 256, 0, stream>>>(u2e, off_s, idx_s, NU, A);
  gmean_kernel<<<(NU * 64 + 255) / 256, 256, 0, stream>>>(v2e, off_ru, idx_ru, NU, Cb);
  gmean_kernel<<<(NV * 64 + 255) / 256, 256, 0, stream>>>(u2e, off_v, idx_v, NV, Db);

  hu_kernel<<<(NU + 255) / 256, 256, 0, stream>>>(u2e, wcomb, W_neigh, A, Cb, Eb);
  hv_kernel<<<(NV + 255) / 256, 256, 0, stream>>>(v2e, W_self, b_self, W_neigh, Db, Fb);

  lin_stats_kernel<<<(NU + 255) / 256, 256, 0, stream>>>(Eb, Wur1, bur1, NU, A, stats + 0, stats + 64);
  lin_stats_kernel<<<(NV + 255) / 256, 256, 0, stream>>>(Fb, Wvr1, bvr1, NV, Cb, stats + 128, stats + 192);

  bn_final_kernel<<<1, 64, 0, stream>>>(stats + 0, stats + 64, bn_gamma, bn_beta, (float)NU, 64, bnp);
  bn_final_kernel<<<1, 64, 0, stream>>>(stats + 128, stats + 192, bn_gamma + 64, bn_beta + 64, (float)NV, 64, bnp + 128);

  bnrelu_lin_kernel<<<(NU + 255) / 256, 256, 0, stream>>>(A, bnp, Wur2, bur2, NU, Db);
  bnrelu_lin_kernel<<<(NV + 255) / 256, 256, 0, stream>>>(Cb, bnp + 128, Wvr2, bvr2, NV, Eb);

  e1_kernel<<<2048, 256, 0, stream>>>(Db, Eb, rates_src, rates_dst, Wuv1, buv1, y1T,
                                      stats + 256, stats + 320);
  bn_final_kernel<<<1, 64, 0, stream>>>(stats + 256, stats + 320, bn_gamma + 128, bn_beta + 128,
                                        (float)ER, 64, bnp + 256);
  e2_kernel<<<2048, 256, 0, stream>>>(y1T, bnp + 256, Wuv2, buv2, y2T,
                                      stats + 384, stats + 400);
  bn_final_kernel<<<1, 16, 0, stream>>>(stats + 384, stats + 400, bn4_gamma, bn4_beta,
                                        (float)ER, 16, bnp + 384);
  e3_kernel<<<(ER + 255) / 256, 256, 0, stream>>>(y2T, bnp + 384, Wuv3, buv3, out);
}

// Round 10
// 1051.138 us; speedup vs baseline: 2.2303x; 1.0832x over previous
//
#include <hip/hip_runtime.h>

#define NU 50000
#define NV 50000
#define ES 800000
#define ER 1000000
#define EPS_BN 1e-5f

// ---------------- workspace layout ----------------
// floats:
static const size_t OFF_A       = 0;         // mean_soc -> t_u
static const size_t OFF_C       = 3350000;   // mean_ru -> t_v
static const size_t OFF_D       = 6550000;   // mean_v  -> x_u
static const size_t OFF_E       = 9750000;   // h_u     -> x_v
static const size_t OFF_F       = 12950000;  // h_v
static const size_t OFF_WCOMB   = 16150000;
static const size_t OFF_STATS   = 16154160;
static const size_t OFF_BNP     = 16154624;
// bytes:
static const size_t OFF_Y1_BYTES = 64640000;   // y1T: [64][ER] bf16, 128MB (CSR scratch pre-e1)
static const size_t OFF_Y2_BYTES = 192640000;  // y2T: [16][ER] bf16, 32MB
// CSR scratch inside y1 region (byte offsets rel. to OFF_Y1_BYTES), consumed before e1.
// idx arrays are uint16 (node ids < 50000 < 65536).
static const size_t CSR_IDX_S  = 0;          // ES u16
static const size_t CSR_IDX_RU = 3200000;    // ER u16
static const size_t CSR_IDX_V  = 7200000;    // ER u16
static const size_t CSR_CNT_S  = 11200000;
static const size_t CSR_CNT_RU = 11400000;
static const size_t CSR_CNT_V  = 11600000;
static const size_t CSR_CUR_S  = 11800000;
static const size_t CSR_CUR_RU = 12000000;
static const size_t CSR_CUR_V  = 12200000;
static const size_t CSR_OFF_S  = 12400000;
static const size_t CSR_OFF_RU = 12600016;
static const size_t CSR_OFF_V  = 12800032;

#define REP16(M) M(0) M(1) M(2) M(3) M(4) M(5) M(6) M(7) M(8) M(9) M(10) M(11) M(12) M(13) M(14) M(15)
#define REP4(M) M(0) M(1) M(2) M(3)

typedef __attribute__((ext_vector_type(8))) short bf16x8;
typedef __attribute__((ext_vector_type(4))) float f32x4;

// ---------------- helpers ----------------
__device__ __forceinline__ unsigned short f2bf(float f) {
  unsigned u = __float_as_uint(f);
  unsigned r = u + 0x7FFF + ((u >> 16) & 1);   // RNE (finite values)
  return (unsigned short)(r >> 16);
}
__device__ __forceinline__ float bf2f(unsigned short h) {
  return __uint_as_float(((unsigned)h) << 16);
}

__device__ __forceinline__ void fma_row(float xk, const float* __restrict__ wrow, float4* acc) {
  const float4* w = (const float4*)wrow;
#pragma unroll
  for (int j = 0; j < 16; ++j) {
    float4 wv = w[j];
    acc[j].x = fmaf(xk, wv.x, acc[j].x);
    acc[j].y = fmaf(xk, wv.y, acc[j].y);
    acc[j].z = fmaf(xk, wv.z, acc[j].z);
    acc[j].w = fmaf(xk, wv.w, acc[j].w);
  }
}

// ---------------- kernels ----------------
__global__ __launch_bounds__(256) void wcomb_kernel(const float* __restrict__ W_self,
                                                    const float* __restrict__ b_self,
                                                    float* __restrict__ wcomb) {
  int i = blockIdx.x * 256 + threadIdx.x;
  if (i < 4096) wcomb[i] = W_self[i] + W_self[8192 + i];
  if (i < 64) wcomb[4096 + i] = b_self[i] + b_self[128 + i];
}

// Node-partitioned histogram: block handles partition (blockIdx&7); partition p
// owns nodes [p*6250,(p+1)*6250). Under round-robin block->XCD dispatch each
// partition's cnt lines stay in ONE XCD's L2 (perf heuristic, not correctness).
__global__ __launch_bounds__(256) void hist_kernel(const int* __restrict__ sd,
                                                   const int* __restrict__ rs,
                                                   const int* __restrict__ rd,
                                                   int* __restrict__ cnt_s,
                                                   int* __restrict__ cnt_ru,
                                                   int* __restrict__ cnt_v) {
  const int part = blockIdx.x & 7;
  const int lo = part * (NU / 8), hi = lo + (NU / 8);
  const int g = blockIdx.x >> 3;
  const int stride = (gridDim.x >> 3) * 256;
  for (int e = g * 256 + threadIdx.x; e < ER; e += stride) {
    if (e < ES) {
      int d = sd[e];
      if (d >= lo && d < hi) atomicAdd(&cnt_s[d], 1);
    }
    int s = rs[e];
    if (s >= lo && s < hi) atomicAdd(&cnt_ru[s], 1);
    int d2 = rd[e];
    if (d2 >= lo && d2 < hi) atomicAdd(&cnt_v[d2], 1);
  }
}

// 3 blocks; per block: thread-serial chunk sums -> one 1024-wide LDS scan ->
// serial prefix write-out. Writes off[0..n] and cur[0..n-1]=off.
__global__ __launch_bounds__(1024) void scan3_kernel(const int* __restrict__ c0, int n0, int* o0, int* u0,
                                                     const int* __restrict__ c1, int n1, int* o1, int* u1,
                                                     const int* __restrict__ c2, int n2, int* o2, int* u2) {
  const int* c; int n; int* o; int* u;
  if (blockIdx.x == 0) { c = c0; n = n0; o = o0; u = u0; }
  else if (blockIdx.x == 1) { c = c1; n = n1; o = o1; u = u1; }
  else { c = c2; n = n2; o = o2; u = u2; }
  __shared__ int buf[1024];
  int t = threadIdx.x;
  int ch = (n + 1023) >> 10;
  int begin = t * ch;
  int end = begin + ch; if (end > n) end = n; if (begin > n) begin = n;
  int sum = 0;
  for (int i = begin; i < end; ++i) sum += c[i];
  buf[t] = sum;
  __syncthreads();
#pragma unroll
  for (int ofs = 1; ofs < 1024; ofs <<= 1) {
    int v = 0;
    if (t >= ofs) v = buf[t - ofs];
    __syncthreads();
    buf[t] += v;
    __syncthreads();
  }
  int run = buf[t] - sum;   // exclusive prefix of this chunk
  for (int i = begin; i < end; ++i) {
    int v = c[i];
    o[i] = run;
    u[i] = run;
    run += v;
  }
  if (t == 1023) o[n] = run;
}

// Node-partitioned scatter (same partition scheme as hist): each partition's
// idx slots form a CONTIGUOUS 1/8 chunk (off monotone in node id) -> all ~20
// writes per 64B line come from one XCD's L2 before writeback.
__global__ __launch_bounds__(256) void scatter_kernel(const int* __restrict__ ss,
                                                      const int* __restrict__ sd,
                                                      const int* __restrict__ rs,
                                                      const int* __restrict__ rd,
                                                      int* __restrict__ cur_s,
                                                      int* __restrict__ cur_ru,
                                                      int* __restrict__ cur_v,
                                                      unsigned short* __restrict__ idx_s,
                                                      unsigned short* __restrict__ idx_ru,
                                                      unsigned short* __restrict__ idx_v) {
  const int part = blockIdx.x & 7;
  const int lo = part * (NU / 8), hi = lo + (NU / 8);
  const int g = blockIdx.x >> 3;
  const int stride = (gridDim.x >> 3) * 256;
  for (int e = g * 256 + threadIdx.x; e < ER; e += stride) {
    if (e < ES) {
      int d = sd[e];
      if (d >= lo && d < hi) {
        int p = atomicAdd(&cur_s[d], 1);
        idx_s[p] = (unsigned short)ss[e];
      }
    }
    int s = rs[e], d = rd[e];
    if (s >= lo && s < hi) {
      int p = atomicAdd(&cur_ru[s], 1);
      idx_ru[p] = (unsigned short)d;
    }
    if (d >= lo && d < hi) {
      int q = atomicAdd(&cur_v[d], 1);
      idx_v[q] = (unsigned short)s;
    }
  }
}

__global__ __launch_bounds__(256) void gmean_kernel(const float* __restrict__ tab,
                                                    const int* __restrict__ off,
                                                    const unsigned short* __restrict__ idx, int N,
                                                    float* __restrict__ mean) {
  int wid = (blockIdx.x * 256 + threadIdx.x) >> 6;
  int lane = threadIdx.x & 63;
  if (wid >= N) return;
  int b = off[wid], e = off[wid + 1];
  float acc0 = 0.0f, acc1 = 0.0f, acc2 = 0.0f, acc3 = 0.0f;
  int i = b;
  for (; i + 3 < e; i += 4) {
    int n0 = idx[i], n1 = idx[i + 1], n2 = idx[i + 2], n3 = idx[i + 3];
    acc0 += tab[(size_t)n0 * 64 + lane];
    acc1 += tab[(size_t)n1 * 64 + lane];
    acc2 += tab[(size_t)n2 * 64 + lane];
    acc3 += tab[(size_t)n3 * 64 + lane];
  }
  for (; i < e; ++i) acc0 += tab[(size_t)idx[i] * 64 + lane];
  float acc = (acc0 + acc1) + (acc2 + acc3);
  float inv = (e > b) ? 1.0f / (float)(e - b) : 0.0f;
  mean[(size_t)wid * 64 + lane] = acc * inv;
}

__global__ __launch_bounds__(256) void hu_kernel(const float* __restrict__ u2e,
                                                 const float* __restrict__ wcomb,
                                                 const float* __restrict__ W_neigh,
                                                 const float* __restrict__ mean_soc,
                                                 const float* __restrict__ mean_ru,
                                                 float* __restrict__ h_u) {
  __shared__ float Wc[4096], W0[4096], W2[4096], bc[64];
  for (int i = threadIdx.x; i < 4096; i += 256) {
    Wc[i] = wcomb[i];
    W0[i] = W_neigh[i];
    W2[i] = W_neigh[8192 + i];
  }
  if (threadIdx.x < 64) bc[threadIdx.x] = wcomb[4096 + threadIdx.x];
  __syncthreads();
  int row = blockIdx.x * 256 + threadIdx.x;
  if (row >= NU) return;
  float4 acc[16];
#pragma unroll
  for (int j = 0; j < 16; ++j) acc[j] = ((const float4*)bc)[j];
  const float4* xr = (const float4*)&u2e[(size_t)row * 64];
  const float4* n0 = (const float4*)&mean_soc[(size_t)row * 64];
  const float4* n2 = (const float4*)&mean_ru[(size_t)row * 64];
#pragma unroll 1
  for (int k4 = 0; k4 < 16; ++k4) {
    float4 a = xr[k4], b0 = n0[k4], b2 = n2[k4];
#pragma unroll
    for (int kk = 0; kk < 4; ++kk) {
      int k = k4 * 4 + kk;
      fma_row((&a.x)[kk], &Wc[k * 64], acc);
      fma_row((&b0.x)[kk], &W0[k * 64], acc);
      fma_row((&b2.x)[kk], &W2[k * 64], acc);
    }
  }
  float4* o = (float4*)&h_u[(size_t)row * 64];
#pragma unroll
  for (int j = 0; j < 16; ++j) o[j] = acc[j];
}

__global__ __launch_bounds__(256) void hv_kernel(const float* __restrict__ v2e,
                                                 const float* __restrict__ W_self,
                                                 const float* __restrict__ b_self,
                                                 const float* __restrict__ W_neigh,
                                                 const float* __restrict__ mean_v,
                                                 float* __restrict__ h_v) {
  __shared__ float Ws[4096], Wn[4096], bl[64];
  for (int i = threadIdx.x; i < 4096; i += 256) {
    Ws[i] = W_self[4096 + i];
    Wn[i] = W_neigh[4096 + i];
  }
  if (threadIdx.x < 64) bl[threadIdx.x] = b_self[64 + threadIdx.x];
  __syncthreads();
  int row = blockIdx.x * 256 + threadIdx.x;
  if (row >= NV) return;
  float4 acc[16];
#pragma unroll
  for (int j = 0; j < 16; ++j) acc[j] = ((const float4*)bl)[j];
  const float4* xr = (const float4*)&v2e[(size_t)row * 64];
  const float4* nv = (const float4*)&mean_v[(size_t)row * 64];
#pragma unroll 1
  for (int k4 = 0; k4 < 16; ++k4) {
    float4 a = xr[k4], b0 = nv[k4];
#pragma unroll
    for (int kk = 0; kk < 4; ++kk) {
      int k = k4 * 4 + kk;
      fma_row((&a.x)[kk], &Ws[k * 64], acc);
      fma_row((&b0.x)[kk], &Wn[k * 64], acc);
    }
  }
  float4* o = (float4*)&h_v[(size_t)row * 64];
#pragma unroll
  for (int j = 0; j < 16; ++j) o[j] = acc[j];
}

// ---- lin_stats: thread-per-row, acc in NAMED float4 registers.
#define CSTAT(VAL, IDX) { \
  float s_ = valid ? (VAL) : 0.0f; float q_ = s_ * s_; \
  s_ += __shfl_down(s_, 32, 64); q_ += __shfl_down(q_, 32, 64); \
  s_ += __shfl_down(s_, 16, 64); q_ += __shfl_down(q_, 16, 64); \
  s_ += __shfl_down(s_, 8, 64);  q_ += __shfl_down(q_, 8, 64); \
  s_ += __shfl_down(s_, 4, 64);  q_ += __shfl_down(q_, 4, 64); \
  s_ += __shfl_down(s_, 2, 64);  q_ += __shfl_down(q_, 2, 64); \
  s_ += __shfl_down(s_, 1, 64);  q_ += __shfl_down(q_, 1, 64); \
  if ((threadIdx.x & 63) == 0) { atomicAdd(&s1[IDX], s_); atomicAdd(&s2[IDX], q_); } }

__global__ __launch_bounds__(256) void lin_stats_kernel(const float* __restrict__ in,
                                                        const float* __restrict__ W,
                                                        const float* __restrict__ b, int N,
                                                        float* __restrict__ out,
                                                        float* __restrict__ ssum,
                                                        float* __restrict__ ssq) {
  __shared__ float Wl[4096], bl[64], s1[64], s2[64];
  for (int i = threadIdx.x; i < 4096; i += 256) Wl[i] = W[i];
  if (threadIdx.x < 64) {
    bl[threadIdx.x] = b[threadIdx.x];
    s1[threadIdx.x] = 0.0f;
    s2[threadIdx.x] = 0.0f;
  }
  __syncthreads();
  int row = blockIdx.x * 256 + threadIdx.x;
  bool valid = row < N;
  const float4* bl4 = (const float4*)bl;
#define LS_DECL(I) float4 A##I;
  REP16(LS_DECL)
#define LS_INIT(I) A##I = bl4[I];
  REP16(LS_INIT)
  if (valid) {
    const float4* xr = (const float4*)&in[(size_t)row * 64];
#define LS_FMA(I) { float4 w_ = W4_[I]; \
    A##I.x = fmaf(z_, w_.x, A##I.x); A##I.y = fmaf(z_, w_.y, A##I.y); \
    A##I.z = fmaf(z_, w_.z, A##I.z); A##I.w = fmaf(z_, w_.w, A##I.w); }
#define LS_DOFMA(ZV, K) { float z_ = (ZV); const float4* W4_ = (const float4*)&Wl[(K) * 64]; REP16(LS_FMA) }
#pragma unroll
    for (int k4 = 0; k4 < 16; ++k4) {
      float4 xa = xr[k4];
      LS_DOFMA(xa.x, k4 * 4 + 0)
      LS_DOFMA(xa.y, k4 * 4 + 1)
      LS_DOFMA(xa.z, k4 * 4 + 2)
      LS_DOFMA(xa.w, k4 * 4 + 3)
    }
    float4* o4 = (float4*)&out[(size_t)row * 64];
#define LS_ST(I) o4[I] = A##I;
    REP16(LS_ST)
  }
#define LS_CST(I) CSTAT(A##I.x, 4 * (I) + 0) CSTAT(A##I.y, 4 * (I) + 1) \
                  CSTAT(A##I.z, 4 * (I) + 2) CSTAT(A##I.w, 4 * (I) + 3)
  REP16(LS_CST)
  __syncthreads();
  if (threadIdx.x < 64) {
    atomicAdd(&ssum[threadIdx.x], s1[threadIdx.x]);
    atomicAdd(&ssq[threadIdx.x], s2[threadIdx.x]);
  }
}

__global__ __launch_bounds__(256) void bn_final_kernel(const float* __restrict__ ssum,
                                                       const float* __restrict__ ssq,
                                                       const float* __restrict__ gamma,
                                                       const float* __restrict__ beta,
                                                       float n, int C, float* __restrict__ bnp) {
  int j = threadIdx.x;
  if (j >= C) return;
  float m = ssum[j] / n;
  float var = ssq[j] / n - m * m;
  float s = gamma[j] * rsqrtf(var + EPS_BN);
  bnp[j] = s;
  bnp[C + j] = beta[j] - m * s;
}

__global__ __launch_bounds__(256) void bnrelu_lin_kernel(const float* __restrict__ tin,
                                                         const float* __restrict__ bnp,
                                                         const float* __restrict__ W,
                                                         const float* __restrict__ b, int N,
                                                         float* __restrict__ xout) {
  __shared__ float Wl[4096], bl[64], sc[64], sh[64];
  for (int i = threadIdx.x; i < 4096; i += 256) Wl[i] = W[i];
  if (threadIdx.x < 64) {
    bl[threadIdx.x] = b[threadIdx.x];
    sc[threadIdx.x] = bnp[threadIdx.x];
    sh[threadIdx.x] = bnp[64 + threadIdx.x];
  }
  __syncthreads();
  int row = blockIdx.x * 256 + threadIdx.x;
  if (row >= N) return;
  float4 acc[16];
#pragma unroll
  for (int j = 0; j < 16; ++j) acc[j] = ((const float4*)bl)[j];
  const float4* xr = (const float4*)&tin[(size_t)row * 64];
#pragma unroll 1
  for (int k4 = 0; k4 < 16; ++k4) {
    float4 a = xr[k4];
#pragma unroll
    for (int kk = 0; kk < 4; ++kk) {
      int k = k4 * 4 + kk;
      float z = fmaxf(fmaf((&a.x)[kk], sc[k], sh[k]), 0.0f);
      fma_row(z, &Wl[k * 64], acc);
    }
  }
  float4* o = (float4*)&xout[(size_t)row * 64];
#pragma unroll
  for (int j = 0; j < 16; ++j) o[j] = acc[j];
}

// ---- e1 v3: MFMA. Per 64-edge tile: P(64e x 64k) @ W(64k x 64j) via
// mfma_f32_16x16x32_bf16, double-bf16 (hi/lo). C/D: col=lane&15, row=(lane>>4)*4+reg.
__global__ __launch_bounds__(256) void e1_kernel(const float* __restrict__ xu,
                                                 const float* __restrict__ xv,
                                                 const int* __restrict__ rs,
                                                 const int* __restrict__ rd,
                                                 const float* __restrict__ W,
                                                 const float* __restrict__ b,
                                                 unsigned short* __restrict__ y1T,
                                                 float* __restrict__ ssum,
                                                 float* __restrict__ ssq) {
  __shared__ __attribute__((aligned(16))) unsigned short Phi[4096];  // [64e][64k] swizzled
  __shared__ __attribute__((aligned(16))) unsigned short Plo[4096];
  __shared__ __attribute__((aligned(16))) unsigned short Yt[64 * 66];  // [64j][66e-pad]
  const int lane = threadIdx.x & 63;
  const int wave = threadIdx.x >> 6;     // 0..3
  const int l15 = lane & 15;
  const int lhi = lane >> 4;             // 0..3
  const int j = wave * 16 + l15;         // this lane's output column

  bf16x8 Whi0, Wlo0, Whi1, Wlo1;
#pragma unroll
  for (int i = 0; i < 8; ++i) {
    {
      float w = W[(0 * 32 + lhi * 8 + i) * 64 + j];
      unsigned short h = f2bf(w);
      Whi0[i] = (short)h;
      Wlo0[i] = (short)f2bf(w - bf2f(h));
    }
    {
      float w = W[(1 * 32 + lhi * 8 + i) * 64 + j];
      unsigned short h = f2bf(w);
      Whi1[i] = (short)h;
      Wlo1[i] = (short)f2bf(w - bf2f(h));
    }
  }
  float bj = b[j];
  float ssl = 0.0f, sql = 0.0f;
  f32x4 acc0, acc1, acc2, acc3;
  const int ntiles = ER / 64;   // 15625 exactly
  for (int t = blockIdx.x; t < ntiles; t += gridDim.x) {
    int e0 = t * 64;
#pragma unroll 4
    for (int i = 0; i < 16; ++i) {
      int el = wave * 16 + i;
      int e = e0 + el;
      float p = xu[(size_t)rs[e] * 64 + lane] * xv[(size_t)rd[e] * 64 + lane];
      unsigned short ph = f2bf(p);
      unsigned short pl = f2bf(p - bf2f(ph));
      int idx = (el * 64 + lane) ^ ((el & 7) << 3);
      Phi[idx] = ph;
      Plo[idx] = pl;
    }
    __syncthreads();
    acc0.x = bj; acc0.y = bj; acc0.z = bj; acc0.w = bj;
    acc1 = acc0; acc2 = acc0; acc3 = acc0;
#define E1_MM(MT, KS, WH, WL) { \
      int row_ = (MT) * 16 + l15; \
      int idx_ = (row_ * 64 + (KS) * 32 + lhi * 8) ^ ((row_ & 7) << 3); \
      bf16x8 ah_ = *(const bf16x8*)&Phi[idx_]; \
      bf16x8 al_ = *(const bf16x8*)&Plo[idx_]; \
      acc##MT = __builtin_amdgcn_mfma_f32_16x16x32_bf16(ah_, WH, acc##MT, 0, 0, 0); \
      acc##MT = __builtin_amdgcn_mfma_f32_16x16x32_bf16(al_, WH, acc##MT, 0, 0, 0); \
      acc##MT = __builtin_amdgcn_mfma_f32_16x16x32_bf16(ah_, WL, acc##MT, 0, 0, 0); }
    E1_MM(0, 0, Whi0, Wlo0) E1_MM(1, 0, Whi0, Wlo0) E1_MM(2, 0, Whi0, Wlo0) E1_MM(3, 0, Whi0, Wlo0)
    E1_MM(0, 1, Whi1, Wlo1) E1_MM(1, 1, Whi1, Wlo1) E1_MM(2, 1, Whi1, Wlo1) E1_MM(3, 1, Whi1, Wlo1)
#define E1_EP(MT) { \
      ssl += (acc##MT.x + acc##MT.y) + (acc##MT.z + acc##MT.w); \
      sql = fmaf(acc##MT.x, acc##MT.x, sql); \
      sql = fmaf(acc##MT.y, acc##MT.y, sql); \
      sql = fmaf(acc##MT.z, acc##MT.z, sql); \
      sql = fmaf(acc##MT.w, acc##MT.w, sql); \
      int eb_ = (MT) * 16 + lhi * 4; \
      unsigned v01_ = (unsigned)f2bf(acc##MT.x) | ((unsigned)f2bf(acc##MT.y) << 16); \
      unsigned v23_ = (unsigned)f2bf(acc##MT.z) | ((unsigned)f2bf(acc##MT.w) << 16); \
      *(unsigned*)&Yt[j * 66 + eb_] = v01_; \
      *(unsigned*)&Yt[j * 66 + eb_ + 2] = v23_; }
    REP4(E1_EP)
#pragma unroll 4
    for (int i = 0; i < 16; ++i) {
      int jj = wave * 16 + i;
      __builtin_nontemporal_store(Yt[jj * 66 + lane], &y1T[(size_t)jj * ER + e0 + lane]);
    }
    __syncthreads();
  }
  ssl += __shfl_down(ssl, 32, 64);
  sql += __shfl_down(sql, 32, 64);
  ssl += __shfl_down(ssl, 16, 64);
  sql += __shfl_down(sql, 16, 64);
  if (lhi == 0) {
    atomicAdd(&ssum[j], ssl);
    atomicAdd(&ssq[j], sql);
  }
}

// ---- e2: thread-per-edge on column-major y1T, NAMED register accumulators.
#define ESTAT(SV, QV, IDX) { \
  float s_ = (SV); float q_ = (QV); \
  s_ += __shfl_down(s_, 32, 64); q_ += __shfl_down(q_, 32, 64); \
  s_ += __shfl_down(s_, 16, 64); q_ += __shfl_down(q_, 16, 64); \
  s_ += __shfl_down(s_, 8, 64);  q_ += __shfl_down(q_, 8, 64); \
  s_ += __shfl_down(s_, 4, 64);  q_ += __shfl_down(q_, 4, 64); \
  s_ += __shfl_down(s_, 2, 64);  q_ += __shfl_down(q_, 2, 64); \
  s_ += __shfl_down(s_, 1, 64);  q_ += __shfl_down(q_, 1, 64); \
  if ((threadIdx.x & 63) == 0) { atomicAdd(&s1[IDX], s_); atomicAdd(&s2[IDX], q_); } }

__global__ __launch_bounds__(256) void e2_kernel(const unsigned short* __restrict__ y1T,
                                                 const float* __restrict__ bnp3,
                                                 const float* __restrict__ W,   // [64,16]
                                                 const float* __restrict__ b,   // [16]
                                                 unsigned short* __restrict__ y2T,
                                                 float* __restrict__ ssum,
                                                 float* __restrict__ ssq) {
  __shared__ float Wl[1024], bl[16], sc[64], sh[64], s1[16], s2[16];
  for (int i = threadIdx.x; i < 1024; i += 256) Wl[i] = W[i];
  if (threadIdx.x < 16) {
    bl[threadIdx.x] = b[threadIdx.x];
    s1[threadIdx.x] = 0.0f;
    s2[threadIdx.x] = 0.0f;
  }
  if (threadIdx.x < 64) { sc[threadIdx.x] = bnp3[threadIdx.x]; sh[threadIdx.x] = bnp3[64 + threadIdx.x]; }
  __syncthreads();
  const float4* bl4 = (const float4*)bl;
  const float4* Wl4 = (const float4*)Wl;
#define E2_DECL(I) float4 B##I; \
  float4 SA##I = make_float4(0.f, 0.f, 0.f, 0.f); \
  float4 SQ##I = make_float4(0.f, 0.f, 0.f, 0.f);
  REP4(E2_DECL)
  int stride = gridDim.x * 256;
  for (int e = blockIdx.x * 256 + threadIdx.x; e < ER; e += stride) {
#define E2_INIT(I) B##I = bl4[I];
    REP4(E2_INIT)
#pragma unroll 4
    for (int k = 0; k < 64; ++k) {
      unsigned short yv = __builtin_nontemporal_load(&y1T[(size_t)k * ER + e]);
      float z = fmaxf(fmaf(bf2f(yv), sc[k], sh[k]), 0.0f);
#define E2_FMA(I) { float4 w_ = Wl4[(k << 2) + (I)]; \
      B##I.x = fmaf(z, w_.x, B##I.x); B##I.y = fmaf(z, w_.y, B##I.y); \
      B##I.z = fmaf(z, w_.z, B##I.z); B##I.w = fmaf(z, w_.w, B##I.w); }
      REP4(E2_FMA)
    }
#define E2_OUT(I) \
    __builtin_nontemporal_store(f2bf(B##I.x), &y2T[(size_t)(4 * (I) + 0) * ER + e]); SA##I.x += B##I.x; SQ##I.x = fmaf(B##I.x, B##I.x, SQ##I.x); \
    __builtin_nontemporal_store(f2bf(B##I.y), &y2T[(size_t)(4 * (I) + 1) * ER + e]); SA##I.y += B##I.y; SQ##I.y = fmaf(B##I.y, B##I.y, SQ##I.y); \
    __builtin_nontemporal_store(f2bf(B##I.z), &y2T[(size_t)(4 * (I) + 2) * ER + e]); SA##I.z += B##I.z; SQ##I.z = fmaf(B##I.z, B##I.z, SQ##I.z); \
    __builtin_nontemporal_store(f2bf(B##I.w), &y2T[(size_t)(4 * (I) + 3) * ER + e]); SA##I.w += B##I.w; SQ##I.w = fmaf(B##I.w, B##I.w, SQ##I.w);
    REP4(E2_OUT)
  }
#define E2_RED(I) ESTAT(SA##I.x, SQ##I.x, 4 * (I) + 0) ESTAT(SA##I.y, SQ##I.y, 4 * (I) + 1) \
                  ESTAT(SA##I.z, SQ##I.z, 4 * (I) + 2) ESTAT(SA##I.w, SQ##I.w, 4 * (I) + 3)
  REP4(E2_RED)
  __syncthreads();
  if (threadIdx.x < 16) {
    atomicAdd(&ssum[threadIdx.x], s1[threadIdx.x]);
    atomicAdd(&ssq[threadIdx.x], s2[threadIdx.x]);
  }
}

__global__ __launch_bounds__(256) void e3_kernel(const unsigned short* __restrict__ y2T,
                                                 const float* __restrict__ bnp4,
                                                 const float* __restrict__ w3,
                                                 const float* __restrict__ b3,
                                                 float* __restrict__ out) {
  __shared__ float sc[16], sh[16], wl[16];
  if (threadIdx.x < 16) {
    sc[threadIdx.x] = bnp4[threadIdx.x];
    sh[threadIdx.x] = bnp4[16 + threadIdx.x];
    wl[threadIdx.x] = w3[threadIdx.x];
  }
  __syncthreads();
  int e = blockIdx.x * 256 + threadIdx.x;
  if (e >= ER) return;
  float acc = b3[0];
#pragma unroll
  for (int j = 0; j < 16; ++j) {
    unsigned short yv = __builtin_nontemporal_load(&y2T[(size_t)j * ER + e]);
    float z = fmaxf(fmaf(bf2f(yv), sc[j], sh[j]), 0.0f);
    acc = fmaf(z, wl[j], acc);
  }
  out[e] = acc;
}

// ---------------- host ----------------
extern "C" void kernel_launch(void* const* d_in, const int* in_sizes, int n_in,
                              void* d_out, int out_size, void* d_ws, size_t ws_size,
                              hipStream_t stream) {
  const float* u2e = (const float*)d_in[0];
  const float* v2e = (const float*)d_in[1];
  const float* W_self = (const float*)d_in[2];
  const float* b_self = (const float*)d_in[3];
  const float* W_neigh = (const float*)d_in[4];
  const float* Wur1 = (const float*)d_in[5];
  const float* bur1 = (const float*)d_in[6];
  const float* Wur2 = (const float*)d_in[7];
  const float* bur2 = (const float*)d_in[8];
  const float* Wvr1 = (const float*)d_in[9];
  const float* bvr1 = (const float*)d_in[10];
  const float* Wvr2 = (const float*)d_in[11];
  const float* bvr2 = (const float*)d_in[12];
  const float* Wuv1 = (const float*)d_in[13];
  const float* buv1 = (const float*)d_in[14];
  const float* Wuv2 = (const float*)d_in[15];
  const float* buv2 = (const float*)d_in[16];
  const float* Wuv3 = (const float*)d_in[17];
  const float* buv3 = (const float*)d_in[18];
  const float* bn_gamma = (const float*)d_in[19];
  const float* bn_beta = (const float*)d_in[20];
  const float* bn4_gamma = (const float*)d_in[21];
  const float* bn4_beta = (const float*)d_in[22];
  const int* social_src = (const int*)d_in[23];
  const int* social_dst = (const int*)d_in[24];
  const int* rates_src = (const int*)d_in[25];
  const int* rates_dst = (const int*)d_in[26];
  float* out = (float*)d_out;
  float* ws = (float*)d_ws;

  float* A = ws + OFF_A;
  float* Cb = ws + OFF_C;
  float* Db = ws + OFF_D;
  float* Eb = ws + OFF_E;
  float* Fb = ws + OFF_F;
  float* wcomb = ws + OFF_WCOMB;
  float* stats = ws + OFF_STATS;
  float* bnp = ws + OFF_BNP;
  char* y1base = (char*)d_ws + OFF_Y1_BYTES;
  unsigned short* idx_s  = (unsigned short*)(y1base + CSR_IDX_S);
  unsigned short* idx_ru = (unsigned short*)(y1base + CSR_IDX_RU);
  unsigned short* idx_v  = (unsigned short*)(y1base + CSR_IDX_V);
  int* cnt_s  = (int*)(y1base + CSR_CNT_S);
  int* cnt_ru = (int*)(y1base + CSR_CNT_RU);
  int* cnt_v  = (int*)(y1base + CSR_CNT_V);
  int* cur_s  = (int*)(y1base + CSR_CUR_S);
  int* cur_ru = (int*)(y1base + CSR_CUR_RU);
  int* cur_v  = (int*)(y1base + CSR_CUR_V);
  int* off_s  = (int*)(y1base + CSR_OFF_S);
  int* off_ru = (int*)(y1base + CSR_OFF_RU);
  int* off_v  = (int*)(y1base + CSR_OFF_V);
  unsigned short* y1T = (unsigned short*)y1base;
  unsigned short* y2T = (unsigned short*)((char*)d_ws + OFF_Y2_BYTES);

  hipMemsetAsync(cnt_s, 0, 3 * (size_t)NU * sizeof(int), stream);
  hipMemsetAsync(stats, 0, 464 * sizeof(float), stream);

  wcomb_kernel<<<16, 256, 0, stream>>>(W_self, b_self, wcomb);

  hist_kernel<<<2048, 256, 0, stream>>>(social_dst, rates_src, rates_dst, cnt_s, cnt_ru, cnt_v);
  scan3_kernel<<<3, 1024, 0, stream>>>(cnt_s, NU, off_s, cur_s,
                                       cnt_ru, NU, off_ru, cur_ru,
                                       cnt_v, NV, off_v, cur_v);
  scatter_kernel<<<2048, 256, 0, stream>>>(social_src, social_dst, rates_src, rates_dst,
                                           cur_s, cur_ru, cur_v, idx_s, idx_ru, idx_v);
  gmean_kernel<<<(NU * 64 + 255) / 256, 256, 0, stream>>>(u2e, off_s, idx_s, NU, A);
  gmean_kernel<<<(NU * 64 + 255) / 256, 256, 0, stream>>>(v2e, off_ru, idx_ru, NU, Cb);
  gmean_kernel<<<(NV * 64 + 255) / 256, 256, 0, stream>>>(u2e, off_v, idx_v, NV, Db);

  hu_kernel<<<(NU + 255) / 256, 256, 0, stream>>>(u2e, wcomb, W_neigh, A, Cb, Eb);
  hv_kernel<<<(NV + 255) / 256, 256, 0, stream>>>(v2e, W_self, b_self, W_neigh, Db, Fb);

  lin_stats_kernel<<<(NU + 255) / 256, 256, 0, stream>>>(Eb, Wur1, bur1, NU, A, stats + 0, stats + 64);
  lin_stats_kernel<<<(NV + 255) / 256, 256, 0, stream>>>(Fb, Wvr1, bvr1, NV, Cb, stats + 128, stats + 192);

  bn_final_kernel<<<1, 64, 0, stream>>>(stats + 0, stats + 64, bn_gamma, bn_beta, (float)NU, 64, bnp);
  bn_final_kernel<<<1, 64, 0, stream>>>(stats + 128, stats + 192, bn_gamma + 64, bn_beta + 64, (float)NV, 64, bnp + 128);

  bnrelu_lin_kernel<<<(NU + 255) / 256, 256, 0, stream>>>(A, bnp, Wur2, bur2, NU, Db);
  bnrelu_lin_kernel<<<(NV + 255) / 256, 256, 0, stream>>>(Cb, bnp + 128, Wvr2, bvr2, NV, Eb);

  e1_kernel<<<2048, 256, 0, stream>>>(Db, Eb, rates_src, rates_dst, Wuv1, buv1, y1T,
                                      stats + 256, stats + 320);
  bn_final_kernel<<<1, 64, 0, stream>>>(stats + 256, stats + 320, bn_gamma + 128, bn_beta + 128,
                                        (float)ER, 64, bnp + 256);
  e2_kernel<<<2048, 256, 0, stream>>>(y1T, bnp + 256, Wuv2, buv2, y2T,
                                      stats + 384, stats + 400);
  bn_final_kernel<<<1, 16, 0, stream>>>(stats + 384, stats + 400, bn4_gamma, bn4_beta,
                                        (float)ER, 16, bnp + 384);
  e3_kernel<<<(ER + 255) / 256, 256, 0, stream>>>(y2T, bnp + 384, Wuv3, buv3, out);
}